// Round 3
// baseline (382.758 us; speedup 1.0000x reference)
//
#include <hip/hip_runtime.h>
#include <math.h>

#define NB_B 2
#define NB_N 4096
#define NB_DIM 1024
#define NB_H 16
#define NB_D 64
#define NB_CTX 3072
#define NSPLIT 6
// 0.125 * log2(e): folds softmax base-2 conversion into q scale
#define QSCALE 0.18033688011112042f

typedef __attribute__((ext_vector_type(8))) short short8;
typedef __attribute__((ext_vector_type(4))) float f32x4;

__device__ __forceinline__ unsigned short f2bf(float f) {
  union { float f; unsigned u; } v; v.f = f;
  unsigned r = v.u + 0x7fffu + ((v.u >> 16) & 1u);
  return (unsigned short)(r >> 16);
}

__device__ __forceinline__ void async16(const void* g, void* l) {
  typedef const unsigned int __attribute__((address_space(1)))* gas_t;
  typedef unsigned int __attribute__((address_space(3)))* las_t;
  __builtin_amdgcn_global_load_lds((gas_t)(unsigned long long)g,
                                   (las_t)(unsigned)(unsigned long long)l,
                                   16, 0, 0);
}

// ---------------- convert x (fp32 -> bf16) ----------------
__global__ void k_conv_x(const float* __restrict__ x, ushort4* __restrict__ xb, int n4) {
  int i = blockIdx.x * blockDim.x + threadIdx.x;
  int stride = gridDim.x * blockDim.x;
  const float4* x4 = (const float4*)x;
  for (; i < n4; i += stride) {
    float4 v = x4[i];
    ushort4 o;
    o.x = f2bf(v.x); o.y = f2bf(v.y); o.z = f2bf(v.z); o.w = f2bf(v.w);
    xb[i] = o;
  }
}

// ---------------- rope cos/sin table: tab[n*32+fi] = (cos, sin)(n * inv_fi) ----------------
__global__ void k_tab(float2* __restrict__ tab) {
  int idx = blockIdx.x * blockDim.x + threadIdx.x;   // [0, 131072)
  int n = idx >> 5, fi = idx & 31;
  float inv = exp2f(-(float)fi * (13.287712379549449f / 32.0f));
  float ang = (float)n * inv;
  float s, c;
  sincosf(ang, &s, &c);
  tab[idx] = make_float2(c, s);
}

// ---------------- transpose weights (fp32 [K][C] -> bf16 [C][K]) ----------------
__global__ void k_conv_wT(const float* __restrict__ Wq, const float* __restrict__ Wkv,
                          const float* __restrict__ Wo,
                          unsigned short* __restrict__ WqkvT, unsigned short* __restrict__ WoT) {
  __shared__ float tile[64][65];
  const float* W; unsigned short* out;
  int z = blockIdx.z;
  if (z == 0)      { W = Wq;  out = WqkvT; }
  else if (z == 1) { W = Wkv; out = WqkvT + 1024 * 1024; }
  else             { W = Wo;  out = WoT; }
  int c0 = blockIdx.x * 64, k0 = blockIdx.y * 64;
  int tx = threadIdx.x & 63, ty = threadIdx.x >> 6;
  #pragma unroll
  for (int i = 0; i < 16; ++i) {
    int k = ty + i * 4;
    tile[k][tx] = W[(long)(k0 + k) * 1024 + c0 + tx];
  }
  __syncthreads();
  #pragma unroll
  for (int i = 0; i < 16; ++i) {
    int c = ty + i * 4;
    out[(long)(c0 + c) * 1024 + k0 + tx] = f2bf(tile[tx][c]);
  }
}

// ---------------- QKV GEMM with fused rope + scale (q) / rope + LN (kv) ----------------
// A: xb [8192][1024] bf16, Bt: WqkvT [2048][1024] bf16.
// cols 0..1023 -> q -> rope*QSCALE -> qf[bh][n][d]; cols 1024..2047 -> kv -> rope+LN -> lkv.
__global__ __launch_bounds__(256) void k_gemm_qkv(
    const unsigned short* __restrict__ A,
    const unsigned short* __restrict__ Bt,
    unsigned short* __restrict__ qf,
    unsigned short* __restrict__ lkvp,
    const float2* __restrict__ tab,
    const float* __restrict__ ln_g,
    const float* __restrict__ ln_b)
{
  __shared__ unsigned short As[128 * 32];
  __shared__ unsigned short Bs[128 * 32];
  const int tid = threadIdx.x;
  const int w = tid >> 6, lane = tid & 63;
  const int wr = w >> 1, wc = w & 1;
  const int quad = lane >> 4, l15 = lane & 15;
  const long tm = (long)blockIdx.y * 128, tn = (long)blockIdx.x * 128;
  const int K = 1024;

  f32x4 acc[4][4];
  #pragma unroll
  for (int i = 0; i < 4; ++i)
    #pragma unroll
    for (int j = 0; j < 4; ++j)
      acc[i][j] = (f32x4){0.f, 0.f, 0.f, 0.f};

  const unsigned short* Ag0 = A + (tm + w * 16 + (lane >> 2)) * K + (lane & 3) * 8;
  const unsigned short* Bg0 = Bt + (tn + w * 16 + (lane >> 2)) * K + (lane & 3) * 8;
  const unsigned short* Ag1 = Ag0 + (long)64 * K;
  const unsigned short* Bg1 = Bg0 + (long)64 * K;
  unsigned short* Al0 = &As[(w * 16) * 32];
  unsigned short* Al1 = &As[(64 + w * 16) * 32];
  unsigned short* Bl0 = &Bs[(w * 16) * 32];
  unsigned short* Bl1 = &Bs[(64 + w * 16) * 32];

  for (int k0 = 0; k0 < K; k0 += 32) {
    __syncthreads();
    async16(Ag0 + k0, Al0);
    async16(Ag1 + k0, Al1);
    async16(Bg0 + k0, Bl0);
    async16(Bg1 + k0, Bl1);
    __syncthreads();
    short8 af[4], bfr[4];
    #pragma unroll
    for (int i = 0; i < 4; ++i)
      af[i] = *(const short8*)&As[(wr * 64 + i * 16 + l15) * 32 + quad * 8];
    #pragma unroll
    for (int j = 0; j < 4; ++j)
      bfr[j] = *(const short8*)&Bs[(wc * 64 + j * 16 + l15) * 32 + quad * 8];
    #pragma unroll
    for (int i = 0; i < 4; ++i)
      #pragma unroll
      for (int j = 0; j < 4; ++j)
        acc[i][j] = __builtin_amdgcn_mfma_f32_16x16x32_bf16(af[i], bfr[j], acc[i][j], 0, 0, 0);
  }

  // fused epilogue: this wave's 64 cols == one full head (64-aligned)
  const int col_base = (int)tn + wc * 64;
  const bool is_q = col_base < 1024;
  const int hh = (col_base & 1023) >> 6;
  unsigned short* dst = is_q ? qf : lkvp;
  float g_ln[4], b_ln[4];
  #pragma unroll
  for (int j = 0; j < 4; ++j) { g_ln[j] = ln_g[j * 16 + l15]; b_ln[j] = ln_b[j * 16 + l15]; }

  const int row_base = (int)tm + wr * 64;
  #pragma unroll
  for (int i = 0; i < 4; ++i) {
    #pragma unroll
    for (int r = 0; r < 4; ++r) {
      const int row = row_base + i * 16 + quad * 4 + r;
      const int n = row & 4095, b = row >> 12;
      const float2 cs0 = tab[n * 32 + l15];
      const float2 cs1 = tab[n * 32 + 16 + l15];
      float val[4];
      #pragma unroll
      for (int j = 0; j < 4; ++j) {
        float t = acc[i][j][r], pt = acc[i][j ^ 2][r];
        float2 cs = (j & 1) ? cs1 : cs0;
        float rot = (j < 2) ? -pt : pt;   // d<32 uses -t[d+32], d>=32 uses +t[d-32]
        val[j] = t * cs.x + rot * cs.y;
      }
      unsigned short* orow = dst + ((long)(b * 16 + hh) * NB_N + n) * 64;
      if (is_q) {
        #pragma unroll
        for (int j = 0; j < 4; ++j)
          orow[j * 16 + l15] = f2bf(val[j] * QSCALE);
      } else {
        float s = val[0] + val[1] + val[2] + val[3];
        #pragma unroll
        for (int o = 1; o < 16; o <<= 1) s += __shfl_xor(s, o);
        const float mu = s * 0.015625f;
        float dv[4], vs = 0.f;
        #pragma unroll
        for (int j = 0; j < 4; ++j) { dv[j] = val[j] - mu; vs += dv[j] * dv[j]; }
        #pragma unroll
        for (int o = 1; o < 16; o <<= 1) vs += __shfl_xor(vs, o);
        const float rr = rsqrtf(vs * 0.015625f + 1e-5f);
        #pragma unroll
        for (int j = 0; j < 4; ++j)
          orow[j * 16 + l15] = f2bf(dv[j] * rr * g_ln[j] + b_ln[j]);
      }
    }
  }
}

// ---------------- generic bf16 GEMM (used for final projection) ----------------
__global__ __launch_bounds__(256) void k_gemm_bt(
    const unsigned short* __restrict__ A,
    const unsigned short* __restrict__ Bt,
    float* __restrict__ C,
    const float* __restrict__ bias,
    int K, int ldc)
{
  __shared__ unsigned short As[128 * 32];
  __shared__ unsigned short Bs[128 * 32];
  const int tid = threadIdx.x;
  const int w = tid >> 6, lane = tid & 63;
  const int wr = w >> 1, wc = w & 1;
  const int quad = lane >> 4, l15 = lane & 15;
  const long tm = (long)blockIdx.y * 128, tn = (long)blockIdx.x * 128;

  f32x4 acc[4][4];
  #pragma unroll
  for (int i = 0; i < 4; ++i)
    #pragma unroll
    for (int j = 0; j < 4; ++j)
      acc[i][j] = (f32x4){0.f, 0.f, 0.f, 0.f};

  const unsigned short* Ag0 = A + (tm + w * 16 + (lane >> 2)) * K + (lane & 3) * 8;
  const unsigned short* Bg0 = Bt + (tn + w * 16 + (lane >> 2)) * K + (lane & 3) * 8;
  const unsigned short* Ag1 = Ag0 + (long)64 * K;
  const unsigned short* Bg1 = Bg0 + (long)64 * K;
  unsigned short* Al0 = &As[(w * 16) * 32];
  unsigned short* Al1 = &As[(64 + w * 16) * 32];
  unsigned short* Bl0 = &Bs[(w * 16) * 32];
  unsigned short* Bl1 = &Bs[(64 + w * 16) * 32];

  for (int k0 = 0; k0 < K; k0 += 32) {
    __syncthreads();
    async16(Ag0 + k0, Al0);
    async16(Ag1 + k0, Al1);
    async16(Bg0 + k0, Bl0);
    async16(Bg1 + k0, Bl1);
    __syncthreads();
    short8 af[4], bfr[4];
    #pragma unroll
    for (int i = 0; i < 4; ++i)
      af[i] = *(const short8*)&As[(wr * 64 + i * 16 + l15) * 32 + quad * 8];
    #pragma unroll
    for (int j = 0; j < 4; ++j)
      bfr[j] = *(const short8*)&Bs[(wc * 64 + j * 16 + l15) * 32 + quad * 8];
    #pragma unroll
    for (int i = 0; i < 4; ++i)
      #pragma unroll
      for (int j = 0; j < 4; ++j)
        acc[i][j] = __builtin_amdgcn_mfma_f32_16x16x32_bf16(af[i], bfr[j], acc[i][j], 0, 0, 0);
  }

  #pragma unroll
  for (int j = 0; j < 4; ++j) {
    const long col = tn + wc * 64 + j * 16 + l15;
    const float bv = bias ? bias[col] : 0.0f;
    #pragma unroll
    for (int i = 0; i < 4; ++i) {
      #pragma unroll
      for (int r = 0; r < 4; ++r) {
        const long row = tm + wr * 64 + i * 16 + quad * 4 + r;
        C[row * ldc + col] = acc[i][j][r] + bv;
      }
    }
  }
}

// ---------------- unified flash attention (latent split-K + ctx) ----------------
// blocks [0, 1536):     latent: qb = bx / NSPLIT, s = bx % NSPLIT. Writes partials.
// blocks [1536, 2304):  context block-diag, writes aout directly.
// All softmax math in base-2 domain (log2e folded into QSCALE).
#define NEGF -3.0e38f
__global__ __launch_bounds__(256) void k_attn(
    const unsigned short* __restrict__ qf,
    const unsigned short* __restrict__ lkv,
    unsigned short* __restrict__ attn_out,
    float* __restrict__ Opart,
    float* __restrict__ mpart,
    float* __restrict__ lpart)
{
  __shared__ unsigned short Ks[64 * 72];    // [key][d] padded
  __shared__ unsigned short Vt[64 * 72];    // [d][key ^ (d&56)] swizzled
  __shared__ unsigned short QPs[128 * 72];  // Q staging, then per-wave P regions

  const int tid = threadIdx.x;
  const int w = tid >> 6, lane = tid & 63;
  const int quad = lane >> 4, l15 = lane & 15;

  const int bx = blockIdx.x;
  int bh, q0tok, kstart, kt0, kt1, q0lat, s6 = 0, qb = 0;
  bool latent;
  if (bx < 256 * NSPLIT) {
    latent = true;
    qb = bx / NSPLIT;        // bh*8 + qt
    s6 = bx % NSPLIT;
    bh = qb >> 3;
    q0lat = (qb & 7) * 128;
    q0tok = NB_CTX + q0lat;
    kstart = 0;
    int nkt = (NB_CTX + q0lat + 128) >> 6;   // skip fully-masked tail tiles
    kt0 = (s6 * nkt) / NSPLIT;
    kt1 = ((s6 + 1) * nkt) / NSPLIT;
  } else {
    latent = false;
    int idx = bx - 256 * NSPLIT;
    bh = idx / 24;
    int r2 = idx % 24;
    int seg = r2 >> 1;
    q0lat = 0;
    q0tok = seg * 256 + (r2 & 1) * 128;
    kstart = seg * 256;
    kt0 = 0; kt1 = 4;
  }

  const unsigned short* qbase = qf + ((long)bh * NB_N + q0tok) * 64;
  const unsigned short* kbase = lkv + (long)bh * NB_N * 64;

  #pragma unroll
  for (int p = 0; p < 4; ++p) {
    int ci = p * 256 + tid;
    int row = ci >> 3, dc = ci & 7;
    uint4 v = *(const uint4*)(qbase + row * 64 + dc * 8);
    *(uint4*)&QPs[row * 72 + dc * 8] = v;
  }
  __syncthreads();

  short8 qfr[2][2];
  #pragma unroll
  for (int i = 0; i < 2; ++i)
    #pragma unroll
    for (int kc = 0; kc < 2; ++kc)
      qfr[i][kc] = *(const short8*)&QPs[(w * 32 + i * 16 + l15) * 72 + kc * 32 + quad * 8];

  f32x4 O[2][4];
  float mi[2][4], li[2][4];
  #pragma unroll
  for (int i = 0; i < 2; ++i) {
    #pragma unroll
    for (int j = 0; j < 4; ++j) O[i][j] = (f32x4){0.f, 0.f, 0.f, 0.f};
    #pragma unroll
    for (int r = 0; r < 4; ++r) { mi[i][r] = NEGF; li[i][r] = 0.f; }
  }

  for (int kt = kt0; kt < kt1; ++kt) {
    const int key0 = kstart + kt * 64;
    __syncthreads();
    #pragma unroll
    for (int p = 0; p < 2; ++p) {
      int ci = p * 256 + tid;
      int key = ci >> 3, dc = ci & 7;
      uint4 v = *(const uint4*)(kbase + (long)(key0 + key) * 64 + dc * 8);
      *(uint4*)&Ks[key * 72 + dc * 8] = v;
      const unsigned short* ev = (const unsigned short*)&v;
      const int sw = key ^ (dc * 8);
      #pragma unroll
      for (int j = 0; j < 8; ++j)
        Vt[(dc * 8 + j) * 72 + sw] = ev[j];
    }
    __syncthreads();

    f32x4 sv[2][4];
    #pragma unroll
    for (int i = 0; i < 2; ++i)
      #pragma unroll
      for (int j = 0; j < 4; ++j)
        sv[i][j] = (f32x4){0.f, 0.f, 0.f, 0.f};
    #pragma unroll
    for (int kc = 0; kc < 2; ++kc) {
      short8 kf[4];
      #pragma unroll
      for (int j = 0; j < 4; ++j)
        kf[j] = *(const short8*)&Ks[(j * 16 + l15) * 72 + kc * 32 + quad * 8];
      #pragma unroll
      for (int i = 0; i < 2; ++i)
        #pragma unroll
        for (int j = 0; j < 4; ++j)
          sv[i][j] = __builtin_amdgcn_mfma_f32_16x16x32_bf16(qfr[i][kc], kf[j], sv[i][j], 0, 0, 0);
    }

    if (latent && key0 + 63 >= NB_CTX) {
      #pragma unroll
      for (int j = 0; j < 4; ++j) {
        int gk = key0 + j * 16 + l15;
        if (gk >= NB_CTX) {
          int kl = gk - NB_CTX;
          #pragma unroll
          for (int i = 0; i < 2; ++i)
            #pragma unroll
            for (int r = 0; r < 4; ++r) {
              int qrow = q0lat + w * 32 + i * 16 + quad * 4 + r;
              if (kl > qrow) sv[i][j][r] = NEGF;
            }
        }
      }
    }

    // online softmax, base-2
    #pragma unroll
    for (int i = 0; i < 2; ++i) {
      #pragma unroll
      for (int r = 0; r < 4; ++r) {
        float mx = fmaxf(fmaxf(sv[i][0][r], sv[i][1][r]), fmaxf(sv[i][2][r], sv[i][3][r]));
        #pragma unroll
        for (int o = 1; o < 16; o <<= 1) mx = fmaxf(mx, __shfl_xor(mx, o));
        float mnew = fmaxf(mi[i][r], mx);
        float alpha = exp2f(mi[i][r] - mnew);
        mi[i][r] = mnew;
        float rs = 0.f;
        #pragma unroll
        for (int j = 0; j < 4; ++j) {
          float p = exp2f(sv[i][j][r] - mnew);
          sv[i][j][r] = p;
          rs += p;
        }
        #pragma unroll
        for (int o = 1; o < 16; o <<= 1) rs += __shfl_xor(rs, o);
        li[i][r] = li[i][r] * alpha + rs;
        #pragma unroll
        for (int jd = 0; jd < 4; ++jd) O[i][jd][r] *= alpha;
      }
    }

    const int pbase = w * 2304;
    #pragma unroll
    for (int i = 0; i < 2; ++i)
      #pragma unroll
      for (int j = 0; j < 4; ++j)
        #pragma unroll
        for (int r = 0; r < 4; ++r)
          QPs[pbase + (i * 16 + quad * 4 + r) * 72 + j * 16 + l15] = f2bf(sv[i][j][r]);

    #pragma unroll
    for (int kc = 0; kc < 2; ++kc) {
      short8 pf[2], vf[4];
      #pragma unroll
      for (int i = 0; i < 2; ++i)
        pf[i] = *(const short8*)&QPs[pbase + (i * 16 + l15) * 72 + kc * 32 + quad * 8];
      #pragma unroll
      for (int jd = 0; jd < 4; ++jd) {
        const int row = jd * 16 + l15;
        vf[jd] = *(const short8*)&Vt[row * 72 + ((kc * 32 + quad * 8) ^ (row & 56))];
      }
      #pragma unroll
      for (int i = 0; i < 2; ++i)
        #pragma unroll
        for (int jd = 0; jd < 4; ++jd)
          O[i][jd] = __builtin_amdgcn_mfma_f32_16x16x32_bf16(pf[i], vf[jd], O[i][jd], 0, 0, 0);
    }
  }

  if (latent) {
    const long pb = (long)(s6 * 256 + qb) * 128;
    #pragma unroll
    for (int i = 0; i < 2; ++i) {
      #pragma unroll
      for (int r = 0; r < 4; ++r) {
        const int row = w * 32 + i * 16 + quad * 4 + r;
        if (l15 == 0) { mpart[pb + row] = mi[i][r]; lpart[pb + row] = li[i][r]; }
        float* orow = Opart + (pb + row) * 64;
        #pragma unroll
        for (int jd = 0; jd < 4; ++jd)
          orow[jd * 16 + l15] = O[i][jd][r];
      }
    }
  } else {
    const int b = bh >> 4, h = bh & 15;
    #pragma unroll
    for (int i = 0; i < 2; ++i) {
      #pragma unroll
      for (int r = 0; r < 4; ++r) {
        const float inv_l = 1.0f / li[i][r];
        const long tok = q0tok + w * 32 + i * 16 + quad * 4 + r;
        unsigned short* orow = attn_out + ((long)b * NB_N + tok) * NB_DIM + h * 64;
        #pragma unroll
        for (int jd = 0; jd < 4; ++jd)
          orow[jd * 16 + l15] = f2bf(O[i][jd][r] * inv_l);
      }
    }
  }
}

// ---------------- combine latent split-K partials (base-2 weights) ----------------
__global__ __launch_bounds__(256) void k_combine(
    const float* __restrict__ Opart, const float* __restrict__ mpart,
    const float* __restrict__ lpart, unsigned short* __restrict__ attn_out)
{
  const int qb = blockIdx.x;        // bh*8 + qt
  const int bh = qb >> 3, qt = qb & 7;
  const int b = bh >> 4, h = bh & 15;
  const int row = threadIdx.x >> 1;
  const int dh = (threadIdx.x & 1) * 32;
  float m[NSPLIT], l[NSPLIT];
  float mstar = NEGF;
  #pragma unroll
  for (int s = 0; s < NSPLIT; ++s) {
    m[s] = mpart[(s * 256 + qb) * 128 + row];
    l[s] = lpart[(s * 256 + qb) * 128 + row];
    mstar = fmaxf(mstar, m[s]);
  }
  float wgt[NSPLIT]; float lsum = 0.f;
  #pragma unroll
  for (int s = 0; s < NSPLIT; ++s) { wgt[s] = exp2f(m[s] - mstar); lsum += wgt[s] * l[s]; }
  const float inv = 1.0f / lsum;
  float o[32];
  #pragma unroll
  for (int e = 0; e < 32; ++e) o[e] = 0.f;
  #pragma unroll
  for (int s = 0; s < NSPLIT; ++s) {
    const float4* Op = (const float4*)(Opart + (((long)(s * 256 + qb) * 128 + row) * 64 + dh));
    #pragma unroll
    for (int v = 0; v < 8; ++v) {
      float4 t = Op[v];
      o[v * 4 + 0] += wgt[s] * t.x; o[v * 4 + 1] += wgt[s] * t.y;
      o[v * 4 + 2] += wgt[s] * t.z; o[v * 4 + 3] += wgt[s] * t.w;
    }
  }
  const long tok = NB_CTX + qt * 128 + row;
  unsigned short* orow = attn_out + ((long)b * NB_N + tok) * NB_DIM + h * 64 + dh;
  #pragma unroll
  for (int e = 0; e < 32; e += 4) {
    ushort4 u;
    u.x = f2bf(o[e] * inv);     u.y = f2bf(o[e + 1] * inv);
    u.z = f2bf(o[e + 2] * inv); u.w = f2bf(o[e + 3] * inv);
    *(ushort4*)(orow + e) = u;
  }
}

extern "C" void kernel_launch(void* const* d_in, const int* in_sizes, int n_in,
                              void* d_out, int out_size, void* d_ws, size_t ws_size,
                              hipStream_t stream)
{
  const float* x    = (const float*)d_in[0];
  const float* Wq   = (const float*)d_in[1];
  const float* Wkv  = (const float*)d_in[2];
  const float* Wo   = (const float*)d_in[3];
  const float* bo   = (const float*)d_in[4];
  const float* ln_g = (const float*)d_in[5];
  const float* ln_b = (const float*)d_in[6];
  float* out = (float*)d_out;

  char* ws = (char*)d_ws;
  unsigned short* xb    = (unsigned short*)(ws);                       // [0,16M)
  unsigned short* WqkvT = (unsigned short*)(ws + (size_t)(16 << 20));  // [16,20M)
  unsigned short* WoT   = (unsigned short*)(ws + (size_t)(20 << 20));  // [20,22M)
  float2*         tab   = (float2*)        (ws + (size_t)(22 << 20));  // [22,23M)
  unsigned short* qfb   = (unsigned short*)(ws + (size_t)(24 << 20));  // [24,40M)
  unsigned short* lkv   = (unsigned short*)(ws + (size_t)(40 << 20));  // [40,56M)
  unsigned short* aout  = (unsigned short*)(ws + (size_t)(56 << 20));  // [56,72M)
  float*          Opart = (float*)         (ws + (size_t)(72 << 20));  // [72,120M)
  float*          mpart = (float*)         (ws + (size_t)(120 << 20)); // [120,121M)
  float*          lpart = (float*)         (ws + (size_t)(121 << 20)); // [121,122M)

  hipLaunchKernelGGL(k_conv_x, dim3(2048), dim3(256), 0, stream,
                     x, (ushort4*)xb, (NB_B * NB_N * NB_DIM) / 4);
  hipLaunchKernelGGL(k_tab, dim3(512), dim3(256), 0, stream, tab);
  hipLaunchKernelGGL(k_conv_wT, dim3(16, 16, 3), dim3(256), 0, stream,
                     Wq, Wkv, Wo, WqkvT, WoT);
  hipLaunchKernelGGL(k_gemm_qkv, dim3(16, 64), dim3(256), 0, stream,
                     xb, WqkvT, qfb, lkv, tab, ln_g, ln_b);
  hipLaunchKernelGGL(k_attn, dim3(256 * NSPLIT + 768), dim3(256), 0, stream,
                     qfb, lkv, aout, Opart, mpart, lpart);
  hipLaunchKernelGGL(k_combine, dim3(256), dim3(256), 0, stream,
                     Opart, mpart, lpart, aout);
  hipLaunchKernelGGL(k_gemm_bt, dim3(8, 64), dim3(256), 0, stream,
                     aout, WoT, out, bo, 1024, 1024);
}

// Round 4
// 330.012 us; speedup vs baseline: 1.1598x; 1.1598x over previous
//
#include <hip/hip_runtime.h>
#include <math.h>

#define NB_B 2
#define NB_N 4096
#define NB_DIM 1024
#define NB_H 16
#define NB_D 64
#define NB_CTX 3072
#define NSPLIT 6
// 0.125 * log2(e): folds softmax base-2 conversion into q scale
#define QSCALE 0.18033688011112042f
#define NEGF -3.0e38f

typedef __attribute__((ext_vector_type(8))) short short8;
typedef __attribute__((ext_vector_type(4))) short s4v;
typedef __attribute__((ext_vector_type(4))) float f32x4;

#if __has_builtin(__builtin_amdgcn_mfma_f32_16x16x16bf16_1k)
__device__ __forceinline__ f32x4 mfma16(s4v a, s4v b, f32x4 c) {
  return __builtin_amdgcn_mfma_f32_16x16x16bf16_1k(a, b, c, 0, 0, 0);
}
#else
__device__ __forceinline__ f32x4 mfma16(s4v a, s4v b, f32x4 c) {
  f32x4 d;
  asm volatile("v_mfma_f32_16x16x16_bf16 %0, %1, %2, %3"
               : "=v"(d) : "v"(a), "v"(b), "v"(c));
  return d;
}
#endif

__device__ __forceinline__ unsigned short f2bf(float f) {
  union { float f; unsigned u; } v; v.f = f;
  unsigned r = v.u + 0x7fffu + ((v.u >> 16) & 1u);
  return (unsigned short)(r >> 16);
}

__device__ __forceinline__ void async16(const void* g, void* l) {
  typedef const unsigned int __attribute__((address_space(1)))* gas_t;
  typedef unsigned int __attribute__((address_space(3)))* las_t;
  __builtin_amdgcn_global_load_lds((gas_t)(unsigned long long)g,
                                   (las_t)(unsigned)(unsigned long long)l,
                                   16, 0, 0);
}

// ---------------- merged prep: conv_x | weight transpose | rope table ----------------
__global__ __launch_bounds__(256) void k_prep(
    const float* __restrict__ x,
    const float* __restrict__ Wq, const float* __restrict__ Wkv, const float* __restrict__ Wo,
    unsigned short* __restrict__ xb, unsigned short* __restrict__ WqkvT,
    unsigned short* __restrict__ WoT, float2* __restrict__ tab)
{
  __shared__ float tile[64][65];
  const int bx = blockIdx.x, tid = threadIdx.x;
  if (bx < 2048) {
    const float4* x4 = (const float4*)x;
    ushort4* xb4 = (ushort4*)xb;
    const int n4 = (NB_B * NB_N * NB_DIM) / 4;
    for (int i = bx * 256 + tid; i < n4; i += 2048 * 256) {
      float4 v = x4[i];
      ushort4 o;
      o.x = f2bf(v.x); o.y = f2bf(v.y); o.z = f2bf(v.z); o.w = f2bf(v.w);
      xb4[i] = o;
    }
  } else if (bx < 2816) {
    int idx = bx - 2048;
    int z = idx >> 8, rem = idx & 255;
    const float* W; unsigned short* out;
    if (z == 0)      { W = Wq;  out = WqkvT; }
    else if (z == 1) { W = Wkv; out = WqkvT + 1024 * 1024; }
    else             { W = Wo;  out = WoT; }
    int c0 = (rem & 15) * 64, k0 = (rem >> 4) * 64;
    int tx = tid & 63, ty = tid >> 6;
    #pragma unroll
    for (int i = 0; i < 16; ++i) {
      int k = ty + i * 4;
      tile[k][tx] = W[(long)(k0 + k) * 1024 + c0 + tx];
    }
    __syncthreads();
    #pragma unroll
    for (int i = 0; i < 16; ++i) {
      int c = ty + i * 4;
      out[(long)(c0 + c) * 1024 + k0 + tx] = f2bf(tile[tx][c]);
    }
  } else {
    int idx = (bx - 2816) * 256 + tid;   // [0, 131072)
    int n = idx >> 5, fi = idx & 31;
    float inv = exp2f(-(float)fi * (13.287712379549449f / 32.0f));
    float ang = (float)n * inv;
    float s, c;
    sincosf(ang, &s, &c);
    tab[idx] = make_float2(c, s);
  }
}

// ---------------- QKV GEMM with fused rope + scale (q) / rope + LN (kv) ----------------
__global__ __launch_bounds__(256) void k_gemm_qkv(
    const unsigned short* __restrict__ A,
    const unsigned short* __restrict__ Bt,
    unsigned short* __restrict__ qf,
    unsigned short* __restrict__ lkvp,
    const float2* __restrict__ tab,
    const float* __restrict__ ln_g,
    const float* __restrict__ ln_b)
{
  __shared__ unsigned short As[128 * 32];
  __shared__ unsigned short Bs[128 * 32];
  const int tid = threadIdx.x;
  const int w = tid >> 6, lane = tid & 63;
  const int wr = w >> 1, wc = w & 1;
  const int quad = lane >> 4, l15 = lane & 15;
  const long tm = (long)blockIdx.y * 128, tn = (long)blockIdx.x * 128;
  const int K = 1024;

  f32x4 acc[4][4];
  #pragma unroll
  for (int i = 0; i < 4; ++i)
    #pragma unroll
    for (int j = 0; j < 4; ++j)
      acc[i][j] = (f32x4){0.f, 0.f, 0.f, 0.f};

  const unsigned short* Ag0 = A + (tm + w * 16 + (lane >> 2)) * K + (lane & 3) * 8;
  const unsigned short* Bg0 = Bt + (tn + w * 16 + (lane >> 2)) * K + (lane & 3) * 8;
  const unsigned short* Ag1 = Ag0 + (long)64 * K;
  const unsigned short* Bg1 = Bg0 + (long)64 * K;
  unsigned short* Al0 = &As[(w * 16) * 32];
  unsigned short* Al1 = &As[(64 + w * 16) * 32];
  unsigned short* Bl0 = &Bs[(w * 16) * 32];
  unsigned short* Bl1 = &Bs[(64 + w * 16) * 32];

  for (int k0 = 0; k0 < K; k0 += 32) {
    __syncthreads();
    async16(Ag0 + k0, Al0);
    async16(Ag1 + k0, Al1);
    async16(Bg0 + k0, Bl0);
    async16(Bg1 + k0, Bl1);
    __syncthreads();
    short8 af[4], bfr[4];
    #pragma unroll
    for (int i = 0; i < 4; ++i)
      af[i] = *(const short8*)&As[(wr * 64 + i * 16 + l15) * 32 + quad * 8];
    #pragma unroll
    for (int j = 0; j < 4; ++j)
      bfr[j] = *(const short8*)&Bs[(wc * 64 + j * 16 + l15) * 32 + quad * 8];
    #pragma unroll
    for (int i = 0; i < 4; ++i)
      #pragma unroll
      for (int j = 0; j < 4; ++j)
        acc[i][j] = __builtin_amdgcn_mfma_f32_16x16x32_bf16(af[i], bfr[j], acc[i][j], 0, 0, 0);
  }

  const int col_base = (int)tn + wc * 64;
  const bool is_q = col_base < 1024;
  const int hh = (col_base & 1023) >> 6;
  unsigned short* dst = is_q ? qf : lkvp;
  float g_ln[4], b_ln[4];
  #pragma unroll
  for (int j = 0; j < 4; ++j) { g_ln[j] = ln_g[j * 16 + l15]; b_ln[j] = ln_b[j * 16 + l15]; }

  const int row_base = (int)tm + wr * 64;
  #pragma unroll
  for (int i = 0; i < 4; ++i) {
    #pragma unroll
    for (int r = 0; r < 4; ++r) {
      const int row = row_base + i * 16 + quad * 4 + r;
      const int n = row & 4095, b = row >> 12;
      const float2 cs0 = tab[n * 32 + l15];
      const float2 cs1 = tab[n * 32 + 16 + l15];
      float val[4];
      #pragma unroll
      for (int j = 0; j < 4; ++j) {
        float t = acc[i][j][r], pt = acc[i][j ^ 2][r];
        float2 cs = (j & 1) ? cs1 : cs0;
        float rot = (j < 2) ? -pt : pt;
        val[j] = t * cs.x + rot * cs.y;
      }
      unsigned short* orow = dst + ((long)(b * 16 + hh) * NB_N + n) * 64;
      if (is_q) {
        #pragma unroll
        for (int j = 0; j < 4; ++j)
          orow[j * 16 + l15] = f2bf(val[j] * QSCALE);
      } else {
        float s = val[0] + val[1] + val[2] + val[3];
        #pragma unroll
        for (int o = 1; o < 16; o <<= 1) s += __shfl_xor(s, o);
        const float mu = s * 0.015625f;
        float dv[4], vs = 0.f;
        #pragma unroll
        for (int j = 0; j < 4; ++j) { dv[j] = val[j] - mu; vs += dv[j] * dv[j]; }
        #pragma unroll
        for (int o = 1; o < 16; o <<= 1) vs += __shfl_xor(vs, o);
        const float rr = rsqrtf(vs * 0.015625f + 1e-5f);
        #pragma unroll
        for (int j = 0; j < 4; ++j)
          orow[j * 16 + l15] = f2bf(dv[j] * rr * g_ln[j] + b_ln[j]);
      }
    }
  }
}

// ---------------- generic bf16 GEMM (final projection) ----------------
__global__ __launch_bounds__(256) void k_gemm_bt(
    const unsigned short* __restrict__ A,
    const unsigned short* __restrict__ Bt,
    float* __restrict__ C,
    const float* __restrict__ bias,
    int K, int ldc)
{
  __shared__ unsigned short As[128 * 32];
  __shared__ unsigned short Bs[128 * 32];
  const int tid = threadIdx.x;
  const int w = tid >> 6, lane = tid & 63;
  const int wr = w >> 1, wc = w & 1;
  const int quad = lane >> 4, l15 = lane & 15;
  const long tm = (long)blockIdx.y * 128, tn = (long)blockIdx.x * 128;

  f32x4 acc[4][4];
  #pragma unroll
  for (int i = 0; i < 4; ++i)
    #pragma unroll
    for (int j = 0; j < 4; ++j)
      acc[i][j] = (f32x4){0.f, 0.f, 0.f, 0.f};

  const unsigned short* Ag0 = A + (tm + w * 16 + (lane >> 2)) * K + (lane & 3) * 8;
  const unsigned short* Bg0 = Bt + (tn + w * 16 + (lane >> 2)) * K + (lane & 3) * 8;
  const unsigned short* Ag1 = Ag0 + (long)64 * K;
  const unsigned short* Bg1 = Bg0 + (long)64 * K;
  unsigned short* Al0 = &As[(w * 16) * 32];
  unsigned short* Al1 = &As[(64 + w * 16) * 32];
  unsigned short* Bl0 = &Bs[(w * 16) * 32];
  unsigned short* Bl1 = &Bs[(64 + w * 16) * 32];

  for (int k0 = 0; k0 < K; k0 += 32) {
    __syncthreads();
    async16(Ag0 + k0, Al0);
    async16(Ag1 + k0, Al1);
    async16(Bg0 + k0, Bl0);
    async16(Bg1 + k0, Bl1);
    __syncthreads();
    short8 af[4], bfr[4];
    #pragma unroll
    for (int i = 0; i < 4; ++i)
      af[i] = *(const short8*)&As[(wr * 64 + i * 16 + l15) * 32 + quad * 8];
    #pragma unroll
    for (int j = 0; j < 4; ++j)
      bfr[j] = *(const short8*)&Bs[(wc * 64 + j * 16 + l15) * 32 + quad * 8];
    #pragma unroll
    for (int i = 0; i < 4; ++i)
      #pragma unroll
      for (int j = 0; j < 4; ++j)
        acc[i][j] = __builtin_amdgcn_mfma_f32_16x16x32_bf16(af[i], bfr[j], acc[i][j], 0, 0, 0);
  }

  #pragma unroll
  for (int j = 0; j < 4; ++j) {
    const long col = tn + wc * 64 + j * 16 + l15;
    const float bv = bias ? bias[col] : 0.0f;
    #pragma unroll
    for (int i = 0; i < 4; ++i) {
      #pragma unroll
      for (int r = 0; r < 4; ++r) {
        const long row = tm + wr * 64 + i * 16 + quad * 4 + r;
        C[row * ldc + col] = acc[i][j][r] + bv;
      }
    }
  }
}

// ---------------- flash attention, S^T/O^T register-resident formulation ----------------
// S^T = K Q^T via mfma(A=K, B=Q): C-layout [key=quad*4+r][q=l15] == B-operand layout
// of 16x16x16 MFMA (k=quad*4+j) -> P feeds O^T = V^T P^T directly from registers.
__global__ __launch_bounds__(256) void k_attn(
    const unsigned short* __restrict__ qf,
    const unsigned short* __restrict__ lkv,
    unsigned short* __restrict__ attn_out,
    float* __restrict__ Opart,
    float* __restrict__ mpart,
    float* __restrict__ lpart)
{
  __shared__ unsigned short smem[18432];       // 36 KB
  unsigned short* Ks  = smem;                  // [64][72]
  unsigned short* Vt  = smem + 4608;           // [64][72] swizzled: [d][key ^ (d&56)]
  unsigned short* QPs = smem + 9216;           // [128][72] Q staging
  float* smf = (float*)smem;                   // epilogue view [128][68]

  const int tid = threadIdx.x;
  const int w = tid >> 6, lane = tid & 63;
  const int quad = lane >> 4, l15 = lane & 15;

  const int bx = blockIdx.x;
  int bh, q0tok, kstart, kt0, kt1, q0lat, s6 = 0, qb = 0;
  bool latent;
  if (bx < 256 * NSPLIT) {
    latent = true;
    qb = bx / NSPLIT;            // bh*8 + qt
    s6 = bx % NSPLIT;
    bh = qb >> 3;
    q0lat = (qb & 7) * 128;
    q0tok = NB_CTX + q0lat;
    kstart = 0;
    int nkt = (NB_CTX + q0lat + 128) >> 6;
    kt0 = (s6 * nkt) / NSPLIT;
    kt1 = ((s6 + 1) * nkt) / NSPLIT;
  } else {
    latent = false;
    int idx = bx - 256 * NSPLIT;
    bh = idx / 24;
    int r2 = idx % 24;
    int seg = r2 >> 1;
    q0lat = 0;
    q0tok = seg * 256 + (r2 & 1) * 128;
    kstart = seg * 256;
    kt0 = 0; kt1 = 4;
  }

  const unsigned short* qbase = qf + ((long)bh * NB_N + q0tok) * 64;
  const unsigned short* kbase = lkv + (long)bh * NB_N * 64;

  // stage Q tile (128 x 64)
  #pragma unroll
  for (int p = 0; p < 4; ++p) {
    int ci = p * 256 + tid;
    int row = ci >> 3, dc = ci & 7;
    uint4 v = *(const uint4*)(qbase + row * 64 + dc * 8);
    *(uint4*)&QPs[row * 72 + dc * 8] = v;
  }
  __syncthreads();

  short8 qfr[2][2];   // [qg][kc] B-operand: n=q (l15), k=d (quad*8+j)
  #pragma unroll
  for (int qg = 0; qg < 2; ++qg)
    #pragma unroll
    for (int kc = 0; kc < 2; ++kc)
      qfr[qg][kc] = *(const short8*)&QPs[(w * 32 + qg * 16 + l15) * 72 + kc * 32 + quad * 8];

  f32x4 ot[2][4];     // [qg][dtile] O^T: row=d (quad*4+r), col=q (l15)
  float mi[2], li[2];
  #pragma unroll
  for (int qg = 0; qg < 2; ++qg) {
    #pragma unroll
    for (int dt = 0; dt < 4; ++dt) ot[qg][dt] = (f32x4){0.f, 0.f, 0.f, 0.f};
    mi[qg] = NEGF; li[qg] = 0.f;
  }

  for (int kt = kt0; kt < kt1; ++kt) {
    const int key0 = kstart + kt * 64;
    __syncthreads();
    #pragma unroll
    for (int p = 0; p < 2; ++p) {
      int ci = p * 256 + tid;
      int key = ci >> 3, dc = ci & 7;
      uint4 v = *(const uint4*)(kbase + (long)(key0 + key) * 64 + dc * 8);
      *(uint4*)&Ks[key * 72 + dc * 8] = v;
      const unsigned short* ev = (const unsigned short*)&v;
      const int sw = key ^ (dc * 8);
      #pragma unroll
      for (int j = 0; j < 8; ++j)
        Vt[(dc * 8 + j) * 72 + sw] = ev[j];
    }
    __syncthreads();

    // S^T[key][q]
    f32x4 st[2][4];   // [qg][kt4]
    #pragma unroll
    for (int qg = 0; qg < 2; ++qg)
      #pragma unroll
      for (int k4 = 0; k4 < 4; ++k4)
        st[qg][k4] = (f32x4){0.f, 0.f, 0.f, 0.f};
    #pragma unroll
    for (int kc = 0; kc < 2; ++kc) {
      short8 kf[4];
      #pragma unroll
      for (int k4 = 0; k4 < 4; ++k4)
        kf[k4] = *(const short8*)&Ks[(k4 * 16 + l15) * 72 + kc * 32 + quad * 8];
      #pragma unroll
      for (int qg = 0; qg < 2; ++qg)
        #pragma unroll
        for (int k4 = 0; k4 < 4; ++k4)
          st[qg][k4] = __builtin_amdgcn_mfma_f32_16x16x32_bf16(kf[k4], qfr[qg][kc], st[qg][k4], 0, 0, 0);
    }

    // causal mask among latents (key index is in-register now)
    if (latent && key0 + 63 >= NB_CTX) {
      #pragma unroll
      for (int qg = 0; qg < 2; ++qg) {
        const int qrow = q0lat + w * 32 + qg * 16 + l15;
        #pragma unroll
        for (int k4 = 0; k4 < 4; ++k4)
          #pragma unroll
          for (int r = 0; r < 4; ++r) {
            const int kl = key0 + k4 * 16 + quad * 4 + r - NB_CTX;
            if (kl > qrow) st[qg][k4][r] = NEGF;
          }
      }
    }

    // online softmax per q-column (in-lane tree + 2 cross-quad shuffles)
    unsigned int pk[2][4][2];
    #pragma unroll
    for (int qg = 0; qg < 2; ++qg) {
      float mx = st[qg][0][0];
      #pragma unroll
      for (int k4 = 0; k4 < 4; ++k4)
        #pragma unroll
        for (int r = 0; r < 4; ++r) mx = fmaxf(mx, st[qg][k4][r]);
      mx = fmaxf(mx, __shfl_xor(mx, 16));
      mx = fmaxf(mx, __shfl_xor(mx, 32));
      const float mnew = fmaxf(mi[qg], mx);
      const float alpha = __builtin_amdgcn_exp2f(mi[qg] - mnew);
      mi[qg] = mnew;
      float rs = 0.f;
      #pragma unroll
      for (int k4 = 0; k4 < 4; ++k4) {
        unsigned int b[4];
        #pragma unroll
        for (int r = 0; r < 4; ++r) {
          float p = __builtin_amdgcn_exp2f(st[qg][k4][r] - mnew);
          unsigned int pb = __float_as_uint(p) & 0xffff0000u;   // bf16-truncate
          rs += __uint_as_float(pb);                            // l consistent with P
          b[r] = pb;
        }
        pk[qg][k4][0] = __builtin_amdgcn_perm(b[1], b[0], 0x07060302);
        pk[qg][k4][1] = __builtin_amdgcn_perm(b[3], b[2], 0x07060302);
      }
      rs += __shfl_xor(rs, 16);
      rs += __shfl_xor(rs, 32);
      li[qg] = li[qg] * alpha + rs;
      #pragma unroll
      for (int dt = 0; dt < 4; ++dt) {
        ot[qg][dt][0] *= alpha; ot[qg][dt][1] *= alpha;
        ot[qg][dt][2] *= alpha; ot[qg][dt][3] *= alpha;
      }
    }

    // O^T += V^T P^T  (P direct from registers)
    #pragma unroll
    for (int k4 = 0; k4 < 4; ++k4) {
      s4v vf[4];
      const int kb = k4 * 16 + quad * 4;
      #pragma unroll
      for (int dt = 0; dt < 4; ++dt) {
        const int row = dt * 16 + l15;
        vf[dt] = *(const s4v*)&Vt[row * 72 + (kb ^ (row & 56))];
      }
      #pragma unroll
      for (int qg = 0; qg < 2; ++qg) {
        s4v pf;
        ((unsigned int*)&pf)[0] = pk[qg][k4][0];
        ((unsigned int*)&pf)[1] = pk[qg][k4][1];
        #pragma unroll
        for (int dt = 0; dt < 4; ++dt)
          ot[qg][dt] = mfma16(vf[dt], pf, ot[qg][dt]);
      }
    }
  }

  // ---- epilogue ----
  if (latent && quad == 0) {
    const long pb = (long)(s6 * 256 + qb) * 128;
    #pragma unroll
    for (int qg = 0; qg < 2; ++qg) {
      mpart[pb + w * 32 + qg * 16 + l15] = mi[qg];
      lpart[pb + w * 32 + qg * 16 + l15] = li[qg];
    }
  }
  __syncthreads();   // all waves done with Ks/Vt/QPs
  #pragma unroll
  for (int qg = 0; qg < 2; ++qg) {
    const int q = w * 32 + qg * 16 + l15;
    #pragma unroll
    for (int dt = 0; dt < 4; ++dt)
      #pragma unroll
      for (int r = 0; r < 4; ++r)
        smf[q * 68 + dt * 16 + quad * 4 + r] = ot[qg][dt][r];
    if (!latent && quad == 0) smf[q * 68 + 64] = li[qg];
  }
  __syncthreads();
  const int row = tid >> 1, half = tid & 1;
  if (latent) {
    const long pb = (long)(s6 * 256 + qb) * 128;
    float4* dst = (float4*)(Opart + (pb + row) * 64 + half * 32);
    #pragma unroll
    for (int v = 0; v < 8; ++v)
      dst[v] = *(const float4*)&smf[row * 68 + half * 32 + v * 4];
  } else {
    const int b_ = bh >> 4, h_ = bh & 15;
    const float inv = 1.0f / smf[row * 68 + 64];
    const long tok = q0tok + row;
    unsigned short* orow = attn_out + ((long)b_ * NB_N + tok) * NB_DIM + h_ * 64 + half * 32;
    #pragma unroll
    for (int v = 0; v < 8; ++v) {
      float4 t = *(const float4*)&smf[row * 68 + half * 32 + v * 4];
      ushort4 u;
      u.x = f2bf(t.x * inv); u.y = f2bf(t.y * inv);
      u.z = f2bf(t.z * inv); u.w = f2bf(t.w * inv);
      *(ushort4*)(orow + v * 4) = u;
    }
  }
}

// ---------------- combine latent split-K partials (base-2 weights) ----------------
__global__ __launch_bounds__(256) void k_combine(
    const float* __restrict__ Opart, const float* __restrict__ mpart,
    const float* __restrict__ lpart, unsigned short* __restrict__ attn_out)
{
  const int qb = blockIdx.x;        // bh*8 + qt
  const int bh = qb >> 3, qt = qb & 7;
  const int b = bh >> 4, h = bh & 15;
  const int row = threadIdx.x >> 1;
  const int dh = (threadIdx.x & 1) * 32;
  float m[NSPLIT], l[NSPLIT];
  float mstar = NEGF;
  #pragma unroll
  for (int s = 0; s < NSPLIT; ++s) {
    m[s] = mpart[(s * 256 + qb) * 128 + row];
    l[s] = lpart[(s * 256 + qb) * 128 + row];
    mstar = fmaxf(mstar, m[s]);
  }
  float wgt[NSPLIT]; float lsum = 0.f;
  #pragma unroll
  for (int s = 0; s < NSPLIT; ++s) {
    wgt[s] = __builtin_amdgcn_exp2f(m[s] - mstar);
    lsum += wgt[s] * l[s];
  }
  const float inv = 1.0f / lsum;
  float o[32];
  #pragma unroll
  for (int e = 0; e < 32; ++e) o[e] = 0.f;
  #pragma unroll
  for (int s = 0; s < NSPLIT; ++s) {
    const float4* Op = (const float4*)(Opart + (((long)(s * 256 + qb) * 128 + row) * 64 + dh));
    #pragma unroll
    for (int v = 0; v < 8; ++v) {
      float4 t = Op[v];
      o[v * 4 + 0] += wgt[s] * t.x; o[v * 4 + 1] += wgt[s] * t.y;
      o[v * 4 + 2] += wgt[s] * t.z; o[v * 4 + 3] += wgt[s] * t.w;
    }
  }
  const long tok = NB_CTX + qt * 128 + row;
  unsigned short* orow = attn_out + ((long)b * NB_N + tok) * NB_DIM + h * 64 + dh;
  #pragma unroll
  for (int e = 0; e < 32; e += 4) {
    ushort4 u;
    u.x = f2bf(o[e] * inv);     u.y = f2bf(o[e + 1] * inv);
    u.z = f2bf(o[e + 2] * inv); u.w = f2bf(o[e + 3] * inv);
    *(ushort4*)(orow + e) = u;
  }
}

extern "C" void kernel_launch(void* const* d_in, const int* in_sizes, int n_in,
                              void* d_out, int out_size, void* d_ws, size_t ws_size,
                              hipStream_t stream)
{
  const float* x    = (const float*)d_in[0];
  const float* Wq   = (const float*)d_in[1];
  const float* Wkv  = (const float*)d_in[2];
  const float* Wo   = (const float*)d_in[3];
  const float* bo   = (const float*)d_in[4];
  const float* ln_g = (const float*)d_in[5];
  const float* ln_b = (const float*)d_in[6];
  float* out = (float*)d_out;

  char* ws = (char*)d_ws;
  unsigned short* xb    = (unsigned short*)(ws);                       // [0,16M)
  unsigned short* WqkvT = (unsigned short*)(ws + (size_t)(16 << 20));  // [16,20M)
  unsigned short* WoT   = (unsigned short*)(ws + (size_t)(20 << 20));  // [20,22M)
  float2*         tab   = (float2*)        (ws + (size_t)(22 << 20));  // [22,23M)
  unsigned short* qfb   = (unsigned short*)(ws + (size_t)(24 << 20));  // [24,40M)
  unsigned short* lkv   = (unsigned short*)(ws + (size_t)(40 << 20));  // [40,56M)
  unsigned short* aout  = (unsigned short*)(ws + (size_t)(56 << 20));  // [56,72M)
  float*          Opart = (float*)         (ws + (size_t)(72 << 20));  // [72,120M)
  float*          mpart = (float*)         (ws + (size_t)(120 << 20)); // [120,121M)
  float*          lpart = (float*)         (ws + (size_t)(121 << 20)); // [121,122M)

  hipLaunchKernelGGL(k_prep, dim3(3328), dim3(256), 0, stream,
                     x, Wq, Wkv, Wo, xb, WqkvT, WoT, tab);
  hipLaunchKernelGGL(k_gemm_qkv, dim3(16, 64), dim3(256), 0, stream,
                     xb, WqkvT, qfb, lkv, tab, ln_g, ln_b);
  hipLaunchKernelGGL(k_attn, dim3(256 * NSPLIT + 768), dim3(256), 0, stream,
                     qfb, lkv, aout, Opart, mpart, lpart);
  hipLaunchKernelGGL(k_combine, dim3(256), dim3(256), 0, stream,
                     Opart, mpart, lpart, aout);
  hipLaunchKernelGGL(k_gemm_bt, dim3(8, 64), dim3(256), 0, stream,
                     aout, WoT, out, bo, 1024, 1024);
}

// Round 5
// 298.908 us; speedup vs baseline: 1.2805x; 1.1041x over previous
//
#include <hip/hip_runtime.h>
#include <math.h>

#define NB_B 2
#define NB_N 4096
#define NB_DIM 1024
#define NB_H 16
#define NB_D 64
#define NB_CTX 3072
#define NSPLIT 4
// 0.125 * log2(e): folds softmax base-2 conversion into q scale
#define QSCALE 0.18033688011112042f
#define NEGF -3.0e38f

typedef __attribute__((ext_vector_type(8))) short short8;
typedef __attribute__((ext_vector_type(4))) short s4v;
typedef __attribute__((ext_vector_type(4))) float f32x4;

#if __has_builtin(__builtin_amdgcn_mfma_f32_16x16x16bf16_1k)
__device__ __forceinline__ f32x4 mfma16(s4v a, s4v b, f32x4 c) {
  return __builtin_amdgcn_mfma_f32_16x16x16bf16_1k(a, b, c, 0, 0, 0);
}
#else
__device__ __forceinline__ f32x4 mfma16(s4v a, s4v b, f32x4 c) {
  f32x4 d;
  asm volatile("v_mfma_f32_16x16x16_bf16 %0, %1, %2, %3"
               : "=v"(d) : "v"(a), "v"(b), "v"(c));
  return d;
}
#endif

__device__ __forceinline__ unsigned short f2bf(float f) {
  union { float f; unsigned u; } v; v.f = f;
  unsigned r = v.u + 0x7fffu + ((v.u >> 16) & 1u);
  return (unsigned short)(r >> 16);
}

__device__ __forceinline__ void async16(const void* g, void* l) {
  typedef const unsigned int __attribute__((address_space(1)))* gas_t;
  typedef unsigned int __attribute__((address_space(3)))* las_t;
  __builtin_amdgcn_global_load_lds((gas_t)(unsigned long long)g,
                                   (las_t)(unsigned)(unsigned long long)l,
                                   16, 0, 0);
}

// ---------------- merged prep: conv_x | weight transpose | rope table ----------------
__global__ __launch_bounds__(256) void k_prep(
    const float* __restrict__ x,
    const float* __restrict__ Wq, const float* __restrict__ Wkv, const float* __restrict__ Wo,
    unsigned short* __restrict__ xb, unsigned short* __restrict__ WqkvT,
    unsigned short* __restrict__ WoT, float2* __restrict__ tab)
{
  __shared__ float tile[64][65];
  const int bx = blockIdx.x, tid = threadIdx.x;
  if (bx < 2048) {
    const float4* x4 = (const float4*)x;
    ushort4* xb4 = (ushort4*)xb;
    const int n4 = (NB_B * NB_N * NB_DIM) / 4;
    for (int i = bx * 256 + tid; i < n4; i += 2048 * 256) {
      float4 v = x4[i];
      ushort4 o;
      o.x = f2bf(v.x); o.y = f2bf(v.y); o.z = f2bf(v.z); o.w = f2bf(v.w);
      xb4[i] = o;
    }
  } else if (bx < 2816) {
    int idx = bx - 2048;
    int z = idx >> 8, rem = idx & 255;
    const float* W; unsigned short* out;
    if (z == 0)      { W = Wq;  out = WqkvT; }
    else if (z == 1) { W = Wkv; out = WqkvT + 1024 * 1024; }
    else             { W = Wo;  out = WoT; }
    int c0 = (rem & 15) * 64, k0 = (rem >> 4) * 64;
    int tx = tid & 63, ty = tid >> 6;
    #pragma unroll
    for (int i = 0; i < 16; ++i) {
      int k = ty + i * 4;
      tile[k][tx] = W[(long)(k0 + k) * 1024 + c0 + tx];
    }
    __syncthreads();
    #pragma unroll
    for (int i = 0; i < 16; ++i) {
      int c = ty + i * 4;
      out[(long)(c0 + c) * 1024 + k0 + tx] = f2bf(tile[tx][c]);
    }
  } else {
    int idx = (bx - 2816) * 256 + tid;   // [0, 131072)
    int n = idx >> 5, fi = idx & 31;
    float inv = exp2f(-(float)fi * (13.287712379549449f / 32.0f));
    float ang = (float)n * inv;
    float s, c;
    sincosf(ang, &s, &c);
    tab[idx] = make_float2(c, s);
  }
}

// ---------------- QKV GEMM with fused rope + scale (q) / rope + LN (kv) ----------------
__global__ __launch_bounds__(256) void k_gemm_qkv(
    const unsigned short* __restrict__ A,
    const unsigned short* __restrict__ Bt,
    unsigned short* __restrict__ qf,
    unsigned short* __restrict__ lkvp,
    const float2* __restrict__ tab,
    const float* __restrict__ ln_g,
    const float* __restrict__ ln_b)
{
  __shared__ unsigned short As[128 * 32];
  __shared__ unsigned short Bs[128 * 32];
  const int tid = threadIdx.x;
  const int w = tid >> 6, lane = tid & 63;
  const int wr = w >> 1, wc = w & 1;
  const int quad = lane >> 4, l15 = lane & 15;
  const long tm = (long)blockIdx.y * 128, tn = (long)blockIdx.x * 128;
  const int K = 1024;

  f32x4 acc[4][4];
  #pragma unroll
  for (int i = 0; i < 4; ++i)
    #pragma unroll
    for (int j = 0; j < 4; ++j)
      acc[i][j] = (f32x4){0.f, 0.f, 0.f, 0.f};

  const unsigned short* Ag0 = A + (tm + w * 16 + (lane >> 2)) * K + (lane & 3) * 8;
  const unsigned short* Bg0 = Bt + (tn + w * 16 + (lane >> 2)) * K + (lane & 3) * 8;
  const unsigned short* Ag1 = Ag0 + (long)64 * K;
  const unsigned short* Bg1 = Bg0 + (long)64 * K;
  unsigned short* Al0 = &As[(w * 16) * 32];
  unsigned short* Al1 = &As[(64 + w * 16) * 32];
  unsigned short* Bl0 = &Bs[(w * 16) * 32];
  unsigned short* Bl1 = &Bs[(64 + w * 16) * 32];

  for (int k0 = 0; k0 < K; k0 += 32) {
    __syncthreads();
    async16(Ag0 + k0, Al0);
    async16(Ag1 + k0, Al1);
    async16(Bg0 + k0, Bl0);
    async16(Bg1 + k0, Bl1);
    __syncthreads();
    short8 af[4], bfr[4];
    #pragma unroll
    for (int i = 0; i < 4; ++i)
      af[i] = *(const short8*)&As[(wr * 64 + i * 16 + l15) * 32 + quad * 8];
    #pragma unroll
    for (int j = 0; j < 4; ++j)
      bfr[j] = *(const short8*)&Bs[(wc * 64 + j * 16 + l15) * 32 + quad * 8];
    #pragma unroll
    for (int i = 0; i < 4; ++i)
      #pragma unroll
      for (int j = 0; j < 4; ++j)
        acc[i][j] = __builtin_amdgcn_mfma_f32_16x16x32_bf16(af[i], bfr[j], acc[i][j], 0, 0, 0);
  }

  const int col_base = (int)tn + wc * 64;
  const bool is_q = col_base < 1024;
  const int hh = (col_base & 1023) >> 6;
  unsigned short* dst = is_q ? qf : lkvp;
  float g_ln[4], b_ln[4];
  #pragma unroll
  for (int j = 0; j < 4; ++j) { g_ln[j] = ln_g[j * 16 + l15]; b_ln[j] = ln_b[j * 16 + l15]; }

  const int row_base = (int)tm + wr * 64;
  #pragma unroll
  for (int i = 0; i < 4; ++i) {
    #pragma unroll
    for (int r = 0; r < 4; ++r) {
      const int row = row_base + i * 16 + quad * 4 + r;
      const int n = row & 4095, b = row >> 12;
      const float2 cs0 = tab[n * 32 + l15];
      const float2 cs1 = tab[n * 32 + 16 + l15];
      float val[4];
      #pragma unroll
      for (int j = 0; j < 4; ++j) {
        float t = acc[i][j][r], pt = acc[i][j ^ 2][r];
        float2 cs = (j & 1) ? cs1 : cs0;
        float rot = (j < 2) ? -pt : pt;
        val[j] = t * cs.x + rot * cs.y;
      }
      unsigned short* orow = dst + ((long)(b * 16 + hh) * NB_N + n) * 64;
      if (is_q) {
        #pragma unroll
        for (int j = 0; j < 4; ++j)
          orow[j * 16 + l15] = f2bf(val[j] * QSCALE);
      } else {
        float s = val[0] + val[1] + val[2] + val[3];
        #pragma unroll
        for (int o = 1; o < 16; o <<= 1) s += __shfl_xor(s, o);
        const float mu = s * 0.015625f;
        float dv[4], vs = 0.f;
        #pragma unroll
        for (int j = 0; j < 4; ++j) { dv[j] = val[j] - mu; vs += dv[j] * dv[j]; }
        #pragma unroll
        for (int o = 1; o < 16; o <<= 1) vs += __shfl_xor(vs, o);
        const float rr = rsqrtf(vs * 0.015625f + 1e-5f);
        #pragma unroll
        for (int j = 0; j < 4; ++j)
          orow[j * 16 + l15] = f2bf(dv[j] * rr * g_ln[j] + b_ln[j]);
      }
    }
  }
}

// ---------------- generic bf16 GEMM (final projection) ----------------
__global__ __launch_bounds__(256) void k_gemm_bt(
    const unsigned short* __restrict__ A,
    const unsigned short* __restrict__ Bt,
    float* __restrict__ C,
    const float* __restrict__ bias,
    int K, int ldc)
{
  __shared__ unsigned short As[128 * 32];
  __shared__ unsigned short Bs[128 * 32];
  const int tid = threadIdx.x;
  const int w = tid >> 6, lane = tid & 63;
  const int wr = w >> 1, wc = w & 1;
  const int quad = lane >> 4, l15 = lane & 15;
  const long tm = (long)blockIdx.y * 128, tn = (long)blockIdx.x * 128;

  f32x4 acc[4][4];
  #pragma unroll
  for (int i = 0; i < 4; ++i)
    #pragma unroll
    for (int j = 0; j < 4; ++j)
      acc[i][j] = (f32x4){0.f, 0.f, 0.f, 0.f};

  const unsigned short* Ag0 = A + (tm + w * 16 + (lane >> 2)) * K + (lane & 3) * 8;
  const unsigned short* Bg0 = Bt + (tn + w * 16 + (lane >> 2)) * K + (lane & 3) * 8;
  const unsigned short* Ag1 = Ag0 + (long)64 * K;
  const unsigned short* Bg1 = Bg0 + (long)64 * K;
  unsigned short* Al0 = &As[(w * 16) * 32];
  unsigned short* Al1 = &As[(64 + w * 16) * 32];
  unsigned short* Bl0 = &Bs[(w * 16) * 32];
  unsigned short* Bl1 = &Bs[(64 + w * 16) * 32];

  for (int k0 = 0; k0 < K; k0 += 32) {
    __syncthreads();
    async16(Ag0 + k0, Al0);
    async16(Ag1 + k0, Al1);
    async16(Bg0 + k0, Bl0);
    async16(Bg1 + k0, Bl1);
    __syncthreads();
    short8 af[4], bfr[4];
    #pragma unroll
    for (int i = 0; i < 4; ++i)
      af[i] = *(const short8*)&As[(wr * 64 + i * 16 + l15) * 32 + quad * 8];
    #pragma unroll
    for (int j = 0; j < 4; ++j)
      bfr[j] = *(const short8*)&Bs[(wc * 64 + j * 16 + l15) * 32 + quad * 8];
    #pragma unroll
    for (int i = 0; i < 4; ++i)
      #pragma unroll
      for (int j = 0; j < 4; ++j)
        acc[i][j] = __builtin_amdgcn_mfma_f32_16x16x32_bf16(af[i], bfr[j], acc[i][j], 0, 0, 0);
  }

  #pragma unroll
  for (int j = 0; j < 4; ++j) {
    const long col = tn + wc * 64 + j * 16 + l15;
    const float bv = bias ? bias[col] : 0.0f;
    #pragma unroll
    for (int i = 0; i < 4; ++i) {
      #pragma unroll
      for (int r = 0; r < 4; ++r) {
        const long row = tm + wr * 64 + i * 16 + quad * 4 + r;
        C[row * ldc + col] = acc[i][j][r] + bv;
      }
    }
  }
}

// ---------------- flash attention, S^T/O^T formulation, pipelined K-tiles ----------------
// Double-buffered staging: global loads for tile kt+1 issued BEFORE compute of tile kt,
// written to the alternate LDS buffer after compute; ONE barrier per tile.
// buf1 overlays the one-shot Q-staging region (extra barrier after Q-frag load protects it).
__global__ __launch_bounds__(256) void k_attn(
    const unsigned short* __restrict__ qf,
    const unsigned short* __restrict__ lkv,
    unsigned short* __restrict__ attn_out,
    float* __restrict__ Opart,
    float* __restrict__ mpart,
    float* __restrict__ lpart)
{
  __shared__ unsigned short smem[18432];   // 36 KB
  // buf0: Ks0 [0,4608), Vt0 [4608,9216)   (shorts)
  // buf1: Ks1 [9216,13824), Vt1 [13824,18432)  == QPs [9216,18432)
  unsigned short* QPs = smem + 9216;
  float* smf = (float*)smem;               // epilogue view [128][68]

  const int tid = threadIdx.x;
  const int w = tid >> 6, lane = tid & 63;
  const int quad = lane >> 4, l15 = lane & 15;

  const int bx = blockIdx.x;
  int bh, q0tok, kstart, kt0, kt1, q0lat, s6 = 0, qb = 0;
  bool latent;
  if (bx < 256 * NSPLIT) {
    latent = true;
    qb = bx / NSPLIT;            // bh*8 + qt
    s6 = bx % NSPLIT;
    bh = qb >> 3;
    q0lat = (qb & 7) * 128;
    q0tok = NB_CTX + q0lat;
    kstart = 0;
    int nkt = (NB_CTX + q0lat + 128) >> 6;
    kt0 = (s6 * nkt) / NSPLIT;
    kt1 = ((s6 + 1) * nkt) / NSPLIT;
  } else {
    latent = false;
    int idx = bx - 256 * NSPLIT;
    bh = idx / 24;
    int r2 = idx % 24;
    int seg = r2 >> 1;
    q0lat = 0;
    q0tok = seg * 256 + (r2 & 1) * 128;
    kstart = seg * 256;
    kt0 = 0; kt1 = 4;
  }

  const unsigned short* qbase = qf + ((long)bh * NB_N + q0tok) * 64;
  const unsigned short* kbase = lkv + (long)bh * NB_N * 64;

  // per-thread staging coords: thread covers keys skey and skey+32, d-chunk sdc
  const int skey = tid >> 3, sdc = tid & 7;

  uint4 gA, gB;
  {
    const int key0 = kstart + kt0 * 64;
    gA = *(const uint4*)(kbase + (long)(key0 + skey) * 64 + sdc * 8);
    gB = *(const uint4*)(kbase + (long)(key0 + skey + 32) * 64 + sdc * 8);
  }

  // stage Q tile (128 x 64) into QPs (buf1 region)
  #pragma unroll
  for (int p = 0; p < 4; ++p) {
    int ci = p * 256 + tid;
    int row = ci >> 3, dc = ci & 7;
    *(uint4*)&QPs[row * 72 + dc * 8] = *(const uint4*)(qbase + row * 64 + dc * 8);
  }

  // store first K tile into buf0
  {
    unsigned short* Ks = smem;
    unsigned short* Vt = smem + 4608;
    *(uint4*)&Ks[skey * 72 + sdc * 8] = gA;
    *(uint4*)&Ks[(skey + 32) * 72 + sdc * 8] = gB;
    const unsigned short* eA = (const unsigned short*)&gA;
    const unsigned short* eB = (const unsigned short*)&gB;
    const int swA = skey ^ (sdc * 8);
    const int swB = (skey + 32) ^ (sdc * 8);
    #pragma unroll
    for (int j = 0; j < 8; ++j) {
      Vt[(sdc * 8 + j) * 72 + swA] = eA[j];
      Vt[(sdc * 8 + j) * 72 + swB] = eB[j];
    }
  }
  __syncthreads();

  short8 qfr[2][2];   // [qg][kc] B-operand: n=q (l15), k=d (quad*8+j)
  #pragma unroll
  for (int qg = 0; qg < 2; ++qg)
    #pragma unroll
    for (int kc = 0; kc < 2; ++kc)
      qfr[qg][kc] = *(const short8*)&QPs[(w * 32 + qg * 16 + l15) * 72 + kc * 32 + quad * 8];
  __syncthreads();   // QPs now free -> buf1 may be written

  f32x4 ot[2][4];     // [qg][dtile] O^T: row=d (quad*4+r), col=q (l15)
  float mi[2], li[2];
  #pragma unroll
  for (int qg = 0; qg < 2; ++qg) {
    #pragma unroll
    for (int dt = 0; dt < 4; ++dt) ot[qg][dt] = (f32x4){0.f, 0.f, 0.f, 0.f};
    mi[qg] = NEGF; li[qg] = 0.f;
  }

  for (int kt = kt0; kt < kt1; ++kt) {
    const int cur = (kt - kt0) & 1;
    unsigned short* Ks = smem + cur * 9216;
    unsigned short* Vt = Ks + 4608;
    const int key0 = kstart + kt * 64;
    const bool more = (kt + 1 < kt1);

    // prefetch next tile (global -> VGPR), latency overlaps compute below
    if (more) {
      const int key0n = key0 + 64;
      gA = *(const uint4*)(kbase + (long)(key0n + skey) * 64 + sdc * 8);
      gB = *(const uint4*)(kbase + (long)(key0n + skey + 32) * 64 + sdc * 8);
    }

    // S^T[key][q]
    f32x4 st[2][4];   // [qg][k4]
    #pragma unroll
    for (int qg = 0; qg < 2; ++qg)
      #pragma unroll
      for (int k4 = 0; k4 < 4; ++k4)
        st[qg][k4] = (f32x4){0.f, 0.f, 0.f, 0.f};
    #pragma unroll
    for (int kc = 0; kc < 2; ++kc) {
      short8 kf[4];
      #pragma unroll
      for (int k4 = 0; k4 < 4; ++k4)
        kf[k4] = *(const short8*)&Ks[(k4 * 16 + l15) * 72 + kc * 32 + quad * 8];
      #pragma unroll
      for (int qg = 0; qg < 2; ++qg)
        #pragma unroll
        for (int k4 = 0; k4 < 4; ++k4)
          st[qg][k4] = __builtin_amdgcn_mfma_f32_16x16x32_bf16(kf[k4], qfr[qg][kc], st[qg][k4], 0, 0, 0);
    }

    // causal mask among latents
    if (latent && key0 + 63 >= NB_CTX) {
      #pragma unroll
      for (int qg = 0; qg < 2; ++qg) {
        const int qrow = q0lat + w * 32 + qg * 16 + l15;
        #pragma unroll
        for (int k4 = 0; k4 < 4; ++k4)
          #pragma unroll
          for (int r = 0; r < 4; ++r) {
            const int kl = key0 + k4 * 16 + quad * 4 + r - NB_CTX;
            if (kl > qrow) st[qg][k4][r] = NEGF;
          }
      }
    }

    // online softmax per q-column (in-lane tree + 2 cross-quad shuffles)
    unsigned int pk[2][4][2];
    #pragma unroll
    for (int qg = 0; qg < 2; ++qg) {
      float mx = st[qg][0][0];
      #pragma unroll
      for (int k4 = 0; k4 < 4; ++k4)
        #pragma unroll
        for (int r = 0; r < 4; ++r) mx = fmaxf(mx, st[qg][k4][r]);
      mx = fmaxf(mx, __shfl_xor(mx, 16));
      mx = fmaxf(mx, __shfl_xor(mx, 32));
      const float mnew = fmaxf(mi[qg], mx);
      const float alpha = __builtin_amdgcn_exp2f(mi[qg] - mnew);
      mi[qg] = mnew;
      float rs = 0.f;
      #pragma unroll
      for (int k4 = 0; k4 < 4; ++k4) {
        unsigned int b[4];
        #pragma unroll
        for (int r = 0; r < 4; ++r) {
          float p = __builtin_amdgcn_exp2f(st[qg][k4][r] - mnew);
          unsigned int pb = __float_as_uint(p) & 0xffff0000u;   // bf16-truncate
          rs += __uint_as_float(pb);                            // l consistent with P
          b[r] = pb;
        }
        pk[qg][k4][0] = __builtin_amdgcn_perm(b[1], b[0], 0x07060302);
        pk[qg][k4][1] = __builtin_amdgcn_perm(b[3], b[2], 0x07060302);
      }
      rs += __shfl_xor(rs, 16);
      rs += __shfl_xor(rs, 32);
      li[qg] = li[qg] * alpha + rs;
      #pragma unroll
      for (int dt = 0; dt < 4; ++dt) {
        ot[qg][dt][0] *= alpha; ot[qg][dt][1] *= alpha;
        ot[qg][dt][2] *= alpha; ot[qg][dt][3] *= alpha;
      }
    }

    // O^T += V^T P^T  (P direct from registers)
    #pragma unroll
    for (int k4 = 0; k4 < 4; ++k4) {
      s4v vf[4];
      const int kb = k4 * 16 + quad * 4;
      #pragma unroll
      for (int dt = 0; dt < 4; ++dt) {
        const int row = dt * 16 + l15;
        vf[dt] = *(const s4v*)&Vt[row * 72 + (kb ^ (row & 56))];
      }
      #pragma unroll
      for (int qg = 0; qg < 2; ++qg) {
        s4v pf;
        ((unsigned int*)&pf)[0] = pk[qg][k4][0];
        ((unsigned int*)&pf)[1] = pk[qg][k4][1];
        #pragma unroll
        for (int dt = 0; dt < 4; ++dt)
          ot[qg][dt] = mfma16(vf[dt], pf, ot[qg][dt]);
      }
    }

    // store prefetched tile into the other buffer (vmcnt wait lands here)
    if (more) {
      unsigned short* Kn = smem + (cur ^ 1) * 9216;
      unsigned short* Vn = Kn + 4608;
      *(uint4*)&Kn[skey * 72 + sdc * 8] = gA;
      *(uint4*)&Kn[(skey + 32) * 72 + sdc * 8] = gB;
      const unsigned short* eA = (const unsigned short*)&gA;
      const unsigned short* eB = (const unsigned short*)&gB;
      const int swA = skey ^ (sdc * 8);
      const int swB = (skey + 32) ^ (sdc * 8);
      #pragma unroll
      for (int j = 0; j < 8; ++j) {
        Vn[(sdc * 8 + j) * 72 + swA] = eA[j];
        Vn[(sdc * 8 + j) * 72 + swB] = eB[j];
      }
    }
    __syncthreads();
  }

  // ---- epilogue (staging buffers dead after final loop barrier) ----
  if (latent && quad == 0) {
    const long pb = (long)(s6 * 256 + qb) * 128;
    #pragma unroll
    for (int qg = 0; qg < 2; ++qg) {
      mpart[pb + w * 32 + qg * 16 + l15] = mi[qg];
      lpart[pb + w * 32 + qg * 16 + l15] = li[qg];
    }
  }
  #pragma unroll
  for (int qg = 0; qg < 2; ++qg) {
    const int q = w * 32 + qg * 16 + l15;
    #pragma unroll
    for (int dt = 0; dt < 4; ++dt)
      #pragma unroll
      for (int r = 0; r < 4; ++r)
        smf[q * 68 + dt * 16 + quad * 4 + r] = ot[qg][dt][r];
    if (!latent && quad == 0) smf[q * 68 + 64] = li[qg];
  }
  __syncthreads();
  const int row = tid >> 1, half = tid & 1;
  if (latent) {
    const long pb = (long)(s6 * 256 + qb) * 128;
    float4* dst = (float4*)(Opart + (pb + row) * 64 + half * 32);
    #pragma unroll
    for (int v = 0; v < 8; ++v)
      dst[v] = *(const float4*)&smf[row * 68 + half * 32 + v * 4];
  } else {
    const int b_ = bh >> 4, h_ = bh & 15;
    const float inv = 1.0f / smf[row * 68 + 64];
    const long tok = q0tok + row;
    unsigned short* orow = attn_out + ((long)b_ * NB_N + tok) * NB_DIM + h_ * 64 + half * 32;
    #pragma unroll
    for (int v = 0; v < 8; ++v) {
      float4 t = *(const float4*)&smf[row * 68 + half * 32 + v * 4];
      ushort4 u;
      u.x = f2bf(t.x * inv); u.y = f2bf(t.y * inv);
      u.z = f2bf(t.z * inv); u.w = f2bf(t.w * inv);
      *(ushort4*)(orow + v * 4) = u;
    }
  }
}

// ---------------- combine latent split-K partials (base-2 weights) ----------------
__global__ __launch_bounds__(256) void k_combine(
    const float* __restrict__ Opart, const float* __restrict__ mpart,
    const float* __restrict__ lpart, unsigned short* __restrict__ attn_out)
{
  const int qb = blockIdx.x;        // bh*8 + qt
  const int bh = qb >> 3, qt = qb & 7;
  const int b = bh >> 4, h = bh & 15;
  const int row = threadIdx.x >> 1;
  const int dh = (threadIdx.x & 1) * 32;
  float m[NSPLIT], l[NSPLIT];
  float mstar = NEGF;
  #pragma unroll
  for (int s = 0; s < NSPLIT; ++s) {
    m[s] = mpart[(s * 256 + qb) * 128 + row];
    l[s] = lpart[(s * 256 + qb) * 128 + row];
    mstar = fmaxf(mstar, m[s]);
  }
  float wgt[NSPLIT]; float lsum = 0.f;
  #pragma unroll
  for (int s = 0; s < NSPLIT; ++s) {
    wgt[s] = __builtin_amdgcn_exp2f(m[s] - mstar);
    lsum += wgt[s] * l[s];
  }
  const float inv = 1.0f / lsum;
  float o[32];
  #pragma unroll
  for (int e = 0; e < 32; ++e) o[e] = 0.f;
  #pragma unroll
  for (int s = 0; s < NSPLIT; ++s) {
    const float4* Op = (const float4*)(Opart + (((long)(s * 256 + qb) * 128 + row) * 64 + dh));
    #pragma unroll
    for (int v = 0; v < 8; ++v) {
      float4 t = Op[v];
      o[v * 4 + 0] += wgt[s] * t.x; o[v * 4 + 1] += wgt[s] * t.y;
      o[v * 4 + 2] += wgt[s] * t.z; o[v * 4 + 3] += wgt[s] * t.w;
    }
  }
  const long tok = NB_CTX + qt * 128 + row;
  unsigned short* orow = attn_out + ((long)b * NB_N + tok) * NB_DIM + h * 64 + dh;
  #pragma unroll
  for (int e = 0; e < 32; e += 4) {
    ushort4 u;
    u.x = f2bf(o[e] * inv);     u.y = f2bf(o[e + 1] * inv);
    u.z = f2bf(o[e + 2] * inv); u.w = f2bf(o[e + 3] * inv);
    *(ushort4*)(orow + e) = u;
  }
}

extern "C" void kernel_launch(void* const* d_in, const int* in_sizes, int n_in,
                              void* d_out, int out_size, void* d_ws, size_t ws_size,
                              hipStream_t stream)
{
  const float* x    = (const float*)d_in[0];
  const float* Wq   = (const float*)d_in[1];
  const float* Wkv  = (const float*)d_in[2];
  const float* Wo   = (const float*)d_in[3];
  const float* bo   = (const float*)d_in[4];
  const float* ln_g = (const float*)d_in[5];
  const float* ln_b = (const float*)d_in[6];
  float* out = (float*)d_out;

  char* ws = (char*)d_ws;
  unsigned short* xb    = (unsigned short*)(ws);                       // [0,16M)
  unsigned short* WqkvT = (unsigned short*)(ws + (size_t)(16 << 20));  // [16,20M)
  unsigned short* WoT   = (unsigned short*)(ws + (size_t)(20 << 20));  // [20,22M)
  float2*         tab   = (float2*)        (ws + (size_t)(22 << 20));  // [22,23M)
  unsigned short* qfb   = (unsigned short*)(ws + (size_t)(24 << 20));  // [24,40M)
  unsigned short* lkv   = (unsigned short*)(ws + (size_t)(40 << 20));  // [40,56M)
  unsigned short* aout  = (unsigned short*)(ws + (size_t)(56 << 20));  // [56,72M)
  float*          Opart = (float*)         (ws + (size_t)(72 << 20));  // [72,106M)
  float*          mpart = (float*)         (ws + (size_t)(112 << 20)); // [112,113M)
  float*          lpart = (float*)         (ws + (size_t)(113 << 20)); // [113,114M)

  hipLaunchKernelGGL(k_prep, dim3(3328), dim3(256), 0, stream,
                     x, Wq, Wkv, Wo, xb, WqkvT, WoT, tab);
  hipLaunchKernelGGL(k_gemm_qkv, dim3(16, 64), dim3(256), 0, stream,
                     xb, WqkvT, qfb, lkv, tab, ln_g, ln_b);
  hipLaunchKernelGGL(k_attn, dim3(256 * NSPLIT + 768), dim3(256), 0, stream,
                     qfb, lkv, aout, Opart, mpart, lpart);
  hipLaunchKernelGGL(k_combine, dim3(256), dim3(256), 0, stream,
                     Opart, mpart, lpart, aout);
  hipLaunchKernelGGL(k_gemm_bt, dim3(8, 64), dim3(256), 0, stream,
                     aout, WoT, out, bo, 1024, 1024);
}

// Round 6
// 276.317 us; speedup vs baseline: 1.3852x; 1.0818x over previous
//
#include <hip/hip_runtime.h>
#include <math.h>

#define NB_B 2
#define NB_N 4096
#define NB_DIM 1024
#define NB_H 16
#define NB_D 64
#define NB_CTX 3072
#define NSPLIT 4
// 0.125 * log2(e): folds softmax base-2 conversion into q scale
#define QSCALE 0.18033688011112042f
#define NEGF -3.0e38f

typedef __attribute__((ext_vector_type(8))) short short8;
typedef __attribute__((ext_vector_type(4))) short s4v;
typedef __attribute__((ext_vector_type(4))) float f32x4;

#if __has_builtin(__builtin_amdgcn_mfma_f32_16x16x16bf16_1k)
__device__ __forceinline__ f32x4 mfma16(s4v a, s4v b, f32x4 c) {
  return __builtin_amdgcn_mfma_f32_16x16x16bf16_1k(a, b, c, 0, 0, 0);
}
#else
__device__ __forceinline__ f32x4 mfma16(s4v a, s4v b, f32x4 c) {
  f32x4 d;
  asm volatile("v_mfma_f32_16x16x16_bf16 %0, %1, %2, %3"
               : "=v"(d) : "v"(a), "v"(b), "v"(c));
  return d;
}
#endif

__device__ __forceinline__ unsigned short f2bf(float f) {
  union { float f; unsigned u; } v; v.f = f;
  unsigned r = v.u + 0x7fffu + ((v.u >> 16) & 1u);
  return (unsigned short)(r >> 16);
}

__device__ __forceinline__ void async16(const void* g, void* l) {
  typedef const unsigned int __attribute__((address_space(1)))* gas_t;
  typedef unsigned int __attribute__((address_space(3)))* las_t;
  __builtin_amdgcn_global_load_lds((gas_t)(unsigned long long)g,
                                   (las_t)(unsigned)(unsigned long long)l,
                                   16, 0, 0);
}

// ---------------- merged prep: conv_x | weight transpose | rope table ----------------
__global__ __launch_bounds__(256) void k_prep(
    const float* __restrict__ x,
    const float* __restrict__ Wq, const float* __restrict__ Wkv, const float* __restrict__ Wo,
    unsigned short* __restrict__ xb, unsigned short* __restrict__ WqkvT,
    unsigned short* __restrict__ WoT, float2* __restrict__ tab)
{
  __shared__ float tile[64][65];
  const int bx = blockIdx.x, tid = threadIdx.x;
  if (bx < 2048) {
    const float4* x4 = (const float4*)x;
    ushort4* xb4 = (ushort4*)xb;
    const int n4 = (NB_B * NB_N * NB_DIM) / 4;
    for (int i = bx * 256 + tid; i < n4; i += 2048 * 256) {
      float4 v = x4[i];
      ushort4 o;
      o.x = f2bf(v.x); o.y = f2bf(v.y); o.z = f2bf(v.z); o.w = f2bf(v.w);
      xb4[i] = o;
    }
  } else if (bx < 2816) {
    int idx = bx - 2048;
    int z = idx >> 8, rem = idx & 255;
    const float* W; unsigned short* out;
    if (z == 0)      { W = Wq;  out = WqkvT; }
    else if (z == 1) { W = Wkv; out = WqkvT + 1024 * 1024; }
    else             { W = Wo;  out = WoT; }
    int c0 = (rem & 15) * 64, k0 = (rem >> 4) * 64;
    int tx = tid & 63, ty = tid >> 6;
    #pragma unroll
    for (int i = 0; i < 16; ++i) {
      int k = ty + i * 4;
      tile[k][tx] = W[(long)(k0 + k) * 1024 + c0 + tx];
    }
    __syncthreads();
    #pragma unroll
    for (int i = 0; i < 16; ++i) {
      int c = ty + i * 4;
      out[(long)(c0 + c) * 1024 + k0 + tx] = f2bf(tile[tx][c]);
    }
  } else {
    int idx = (bx - 2816) * 256 + tid;   // [0, 131072)
    int n = idx >> 5, fi = idx & 31;
    float inv = exp2f(-(float)fi * (13.287712379549449f / 32.0f));
    float ang = (float)n * inv;
    float s, c;
    sincosf(ang, &s, &c);
    tab[idx] = make_float2(c, s);
  }
}

// ---------------- QKV GEMM with fused rope + scale (q) / rope + LN (kv) ----------------
__global__ __launch_bounds__(256) void k_gemm_qkv(
    const unsigned short* __restrict__ A,
    const unsigned short* __restrict__ Bt,
    unsigned short* __restrict__ qf,
    unsigned short* __restrict__ lkvp,
    const float2* __restrict__ tab,
    const float* __restrict__ ln_g,
    const float* __restrict__ ln_b)
{
  __shared__ unsigned short As[128 * 32];
  __shared__ unsigned short Bs[128 * 32];
  const int tid = threadIdx.x;
  const int w = tid >> 6, lane = tid & 63;
  const int wr = w >> 1, wc = w & 1;
  const int quad = lane >> 4, l15 = lane & 15;
  const long tm = (long)blockIdx.y * 128, tn = (long)blockIdx.x * 128;
  const int K = 1024;

  f32x4 acc[4][4];
  #pragma unroll
  for (int i = 0; i < 4; ++i)
    #pragma unroll
    for (int j = 0; j < 4; ++j)
      acc[i][j] = (f32x4){0.f, 0.f, 0.f, 0.f};

  const unsigned short* Ag0 = A + (tm + w * 16 + (lane >> 2)) * K + (lane & 3) * 8;
  const unsigned short* Bg0 = Bt + (tn + w * 16 + (lane >> 2)) * K + (lane & 3) * 8;
  const unsigned short* Ag1 = Ag0 + (long)64 * K;
  const unsigned short* Bg1 = Bg0 + (long)64 * K;
  unsigned short* Al0 = &As[(w * 16) * 32];
  unsigned short* Al1 = &As[(64 + w * 16) * 32];
  unsigned short* Bl0 = &Bs[(w * 16) * 32];
  unsigned short* Bl1 = &Bs[(64 + w * 16) * 32];

  for (int k0 = 0; k0 < K; k0 += 32) {
    __syncthreads();
    async16(Ag0 + k0, Al0);
    async16(Ag1 + k0, Al1);
    async16(Bg0 + k0, Bl0);
    async16(Bg1 + k0, Bl1);
    __syncthreads();
    short8 af[4], bfr[4];
    #pragma unroll
    for (int i = 0; i < 4; ++i)
      af[i] = *(const short8*)&As[(wr * 64 + i * 16 + l15) * 32 + quad * 8];
    #pragma unroll
    for (int j = 0; j < 4; ++j)
      bfr[j] = *(const short8*)&Bs[(wc * 64 + j * 16 + l15) * 32 + quad * 8];
    #pragma unroll
    for (int i = 0; i < 4; ++i)
      #pragma unroll
      for (int j = 0; j < 4; ++j)
        acc[i][j] = __builtin_amdgcn_mfma_f32_16x16x32_bf16(af[i], bfr[j], acc[i][j], 0, 0, 0);
  }

  const int col_base = (int)tn + wc * 64;
  const bool is_q = col_base < 1024;
  const int hh = (col_base & 1023) >> 6;
  unsigned short* dst = is_q ? qf : lkvp;
  float g_ln[4], b_ln[4];
  #pragma unroll
  for (int j = 0; j < 4; ++j) { g_ln[j] = ln_g[j * 16 + l15]; b_ln[j] = ln_b[j * 16 + l15]; }

  const int row_base = (int)tm + wr * 64;
  #pragma unroll
  for (int i = 0; i < 4; ++i) {
    #pragma unroll
    for (int r = 0; r < 4; ++r) {
      const int row = row_base + i * 16 + quad * 4 + r;
      const int n = row & 4095, b = row >> 12;
      const float2 cs0 = tab[n * 32 + l15];
      const float2 cs1 = tab[n * 32 + 16 + l15];
      float val[4];
      #pragma unroll
      for (int j = 0; j < 4; ++j) {
        float t = acc[i][j][r], pt = acc[i][j ^ 2][r];
        float2 cs = (j & 1) ? cs1 : cs0;
        float rot = (j < 2) ? -pt : pt;
        val[j] = t * cs.x + rot * cs.y;
      }
      unsigned short* orow = dst + ((long)(b * 16 + hh) * NB_N + n) * 64;
      if (is_q) {
        #pragma unroll
        for (int j = 0; j < 4; ++j)
          orow[j * 16 + l15] = f2bf(val[j] * QSCALE);
      } else {
        float s = val[0] + val[1] + val[2] + val[3];
        #pragma unroll
        for (int o = 1; o < 16; o <<= 1) s += __shfl_xor(s, o);
        const float mu = s * 0.015625f;
        float dv[4], vs = 0.f;
        #pragma unroll
        for (int j = 0; j < 4; ++j) { dv[j] = val[j] - mu; vs += dv[j] * dv[j]; }
        #pragma unroll
        for (int o = 1; o < 16; o <<= 1) vs += __shfl_xor(vs, o);
        const float rr = rsqrtf(vs * 0.015625f + 1e-5f);
        #pragma unroll
        for (int j = 0; j < 4; ++j)
          orow[j * 16 + l15] = f2bf(dv[j] * rr * g_ln[j] + b_ln[j]);
      }
    }
  }
}

// ---------------- generic bf16 GEMM (final projection) ----------------
__global__ __launch_bounds__(256) void k_gemm_bt(
    const unsigned short* __restrict__ A,
    const unsigned short* __restrict__ Bt,
    float* __restrict__ C,
    const float* __restrict__ bias,
    int K, int ldc)
{
  __shared__ unsigned short As[128 * 32];
  __shared__ unsigned short Bs[128 * 32];
  const int tid = threadIdx.x;
  const int w = tid >> 6, lane = tid & 63;
  const int wr = w >> 1, wc = w & 1;
  const int quad = lane >> 4, l15 = lane & 15;
  const long tm = (long)blockIdx.y * 128, tn = (long)blockIdx.x * 128;

  f32x4 acc[4][4];
  #pragma unroll
  for (int i = 0; i < 4; ++i)
    #pragma unroll
    for (int j = 0; j < 4; ++j)
      acc[i][j] = (f32x4){0.f, 0.f, 0.f, 0.f};

  const unsigned short* Ag0 = A + (tm + w * 16 + (lane >> 2)) * K + (lane & 3) * 8;
  const unsigned short* Bg0 = Bt + (tn + w * 16 + (lane >> 2)) * K + (lane & 3) * 8;
  const unsigned short* Ag1 = Ag0 + (long)64 * K;
  const unsigned short* Bg1 = Bg0 + (long)64 * K;
  unsigned short* Al0 = &As[(w * 16) * 32];
  unsigned short* Al1 = &As[(64 + w * 16) * 32];
  unsigned short* Bl0 = &Bs[(w * 16) * 32];
  unsigned short* Bl1 = &Bs[(64 + w * 16) * 32];

  for (int k0 = 0; k0 < K; k0 += 32) {
    __syncthreads();
    async16(Ag0 + k0, Al0);
    async16(Ag1 + k0, Al1);
    async16(Bg0 + k0, Bl0);
    async16(Bg1 + k0, Bl1);
    __syncthreads();
    short8 af[4], bfr[4];
    #pragma unroll
    for (int i = 0; i < 4; ++i)
      af[i] = *(const short8*)&As[(wr * 64 + i * 16 + l15) * 32 + quad * 8];
    #pragma unroll
    for (int j = 0; j < 4; ++j)
      bfr[j] = *(const short8*)&Bs[(wc * 64 + j * 16 + l15) * 32 + quad * 8];
    #pragma unroll
    for (int i = 0; i < 4; ++i)
      #pragma unroll
      for (int j = 0; j < 4; ++j)
        acc[i][j] = __builtin_amdgcn_mfma_f32_16x16x32_bf16(af[i], bfr[j], acc[i][j], 0, 0, 0);
  }

  #pragma unroll
  for (int j = 0; j < 4; ++j) {
    const long col = tn + wc * 64 + j * 16 + l15;
    const float bv = bias ? bias[col] : 0.0f;
    #pragma unroll
    for (int i = 0; i < 4; ++i) {
      #pragma unroll
      for (int r = 0; r < 4; ++r) {
        const long row = tm + wr * 64 + i * 16 + quad * 4 + r;
        C[row * ldc + col] = acc[i][j][r] + bv;
      }
    }
  }
}

// ---------------- flash attention: S^T/O^T, 18.4KB LDS, deferred-max softmax ----------------
// Q fragments loaded directly from global (no Q LDS). Single K/V buffer with
// register prefetch. Softmax uses previous-tile max reference (exact; rescale
// by exp2(mi-mnew) AFTER PV -> max-tree off the exp->PV critical path).
__global__ __launch_bounds__(256) void k_attn(
    const unsigned short* __restrict__ qf,
    const unsigned short* __restrict__ lkv,
    unsigned short* __restrict__ attn_out,
    float* __restrict__ Opart,      // transposed: [(s,qb)][d(64)][q(128)]
    float* __restrict__ mpart,
    float* __restrict__ lpart)
{
  __shared__ unsigned short smem[9216];   // 18432 B
  unsigned short* Ks = smem;              // [64][72]
  unsigned short* Vt = smem + 4608;       // [64][72], [d][key ^ (d&56)]

  const int tid = threadIdx.x;
  const int w = tid >> 6, lane = tid & 63;
  const int quad = lane >> 4, l15 = lane & 15;

  const int bx = blockIdx.x;
  int bh, q0tok, kstart, kt0, kt1, q0lat, s6 = 0, qb = 0;
  bool latent;
  if (bx < 256 * NSPLIT) {
    latent = true;
    qb = bx / NSPLIT;            // bh*8 + qt
    s6 = bx % NSPLIT;
    bh = qb >> 3;
    q0lat = (qb & 7) * 128;
    q0tok = NB_CTX + q0lat;
    kstart = 0;
    int nkt = (NB_CTX + q0lat + 128) >> 6;
    kt0 = (s6 * nkt) / NSPLIT;
    kt1 = ((s6 + 1) * nkt) / NSPLIT;
  } else {
    latent = false;
    int idx = bx - 256 * NSPLIT;
    bh = idx / 24;
    int r2 = idx % 24;
    int seg = r2 >> 1;
    q0lat = 0;
    q0tok = seg * 256 + (r2 & 1) * 128;
    kstart = seg * 256;
    kt0 = 0; kt1 = 4;
  }

  const unsigned short* qbase = qf + ((long)bh * NB_N + q0tok) * 64;
  const unsigned short* kbase = lkv + (long)bh * NB_N * 64;

  // Q fragments direct from global (coalesced 16B, 16 rows x 64B segments)
  short8 qfr[2][2];
  #pragma unroll
  for (int qg = 0; qg < 2; ++qg)
    #pragma unroll
    for (int kc = 0; kc < 2; ++kc)
      qfr[qg][kc] = *(const short8*)(qbase + (w * 32 + qg * 16 + l15) * 64 + kc * 32 + quad * 8);

  // staging coords: thread covers adjacent keys 2kp, 2kp+1, d-chunk sdc
  const int kp = tid >> 3, sdc = tid & 7;

  uint4 gA, gB;
  {
    const int key0 = kstart + kt0 * 64;
    gA = *(const uint4*)(kbase + (long)(key0 + 2 * kp) * 64 + sdc * 8);
    gB = *(const uint4*)(kbase + (long)(key0 + 2 * kp + 1) * 64 + sdc * 8);
  }

  f32x4 ot[2][4];     // O^T in 2^-mi units: row=d (quad*4+r), col=q (l15)
  float mi[2], li[2];
  #pragma unroll
  for (int qg = 0; qg < 2; ++qg) {
    #pragma unroll
    for (int dt = 0; dt < 4; ++dt) ot[qg][dt] = (f32x4){0.f, 0.f, 0.f, 0.f};
    mi[qg] = 0.f; li[qg] = 0.f;
  }

  for (int kt = kt0; kt < kt1; ++kt) {
    const int key0 = kstart + kt * 64;
    __syncthreads();              // prev tile fully consumed
    // store staged tile: Ks rows + paired-key transposed Vt (b32 writes)
    *(uint4*)&Ks[(2 * kp) * 72 + sdc * 8] = gA;
    *(uint4*)&Ks[(2 * kp + 1) * 72 + sdc * 8] = gB;
    {
      const unsigned short* eA = (const unsigned short*)&gA;
      const unsigned short* eB = (const unsigned short*)&gB;
      #pragma unroll
      for (int j = 0; j < 8; ++j) {
        const int d = sdc * 8 + j;
        const unsigned int pair = (unsigned int)eA[j] | ((unsigned int)eB[j] << 16);
        *(unsigned int*)&Vt[d * 72 + ((2 * kp) ^ (d & 56))] = pair;
      }
    }
    __syncthreads();              // tile ready
    if (kt + 1 < kt1) {           // prefetch next tile into regs
      const int key0n = key0 + 64;
      gA = *(const uint4*)(kbase + (long)(key0n + 2 * kp) * 64 + sdc * 8);
      gB = *(const uint4*)(kbase + (long)(key0n + 2 * kp + 1) * 64 + sdc * 8);
    }

    // S^T[key][q]
    f32x4 st[2][4];
    #pragma unroll
    for (int qg = 0; qg < 2; ++qg)
      #pragma unroll
      for (int k4 = 0; k4 < 4; ++k4)
        st[qg][k4] = (f32x4){0.f, 0.f, 0.f, 0.f};
    #pragma unroll
    for (int kc = 0; kc < 2; ++kc) {
      short8 kf[4];
      #pragma unroll
      for (int k4 = 0; k4 < 4; ++k4)
        kf[k4] = *(const short8*)&Ks[(k4 * 16 + l15) * 72 + kc * 32 + quad * 8];
      #pragma unroll
      for (int qg = 0; qg < 2; ++qg)
        #pragma unroll
        for (int k4 = 0; k4 < 4; ++k4)
          st[qg][k4] = __builtin_amdgcn_mfma_f32_16x16x32_bf16(kf[k4], qfr[qg][kc], st[qg][k4], 0, 0, 0);
    }

    // causal mask among latents
    if (latent && key0 + 63 >= NB_CTX) {
      #pragma unroll
      for (int qg = 0; qg < 2; ++qg) {
        const int qrow = q0lat + w * 32 + qg * 16 + l15;
        #pragma unroll
        for (int k4 = 0; k4 < 4; ++k4)
          #pragma unroll
          for (int r = 0; r < 4; ++r) {
            const int kl = key0 + k4 * 16 + quad * 4 + r - NB_CTX;
            if (kl > qrow) st[qg][k4][r] = NEGF;
          }
      }
    }

    // deferred-max softmax: exp against PREVIOUS reference mi (exact, rescale later)
    unsigned int pk[2][4][2];
    float tmx[2], trs[2];
    #pragma unroll
    for (int qg = 0; qg < 2; ++qg) {
      float rs = 0.f;
      float mx = st[qg][0][0];
      #pragma unroll
      for (int k4 = 0; k4 < 4; ++k4) {
        unsigned int b[4];
        #pragma unroll
        for (int r = 0; r < 4; ++r) {
          mx = fmaxf(mx, st[qg][k4][r]);
          float p = __builtin_amdgcn_exp2f(st[qg][k4][r] - mi[qg]);
          unsigned int pb = __float_as_uint(p) & 0xffff0000u;   // bf16-truncate
          rs += __uint_as_float(pb);
          b[r] = pb;
        }
        pk[qg][k4][0] = __builtin_amdgcn_perm(b[1], b[0], 0x07060302);
        pk[qg][k4][1] = __builtin_amdgcn_perm(b[3], b[2], 0x07060302);
      }
      tmx[qg] = mx; trs[qg] = rs;
    }

    // O^T += V^T P^T  (P direct from registers)
    #pragma unroll
    for (int k4 = 0; k4 < 4; ++k4) {
      s4v vf[4];
      const int kb = k4 * 16 + quad * 4;
      #pragma unroll
      for (int dt = 0; dt < 4; ++dt) {
        const int row = dt * 16 + l15;
        vf[dt] = *(const s4v*)&Vt[row * 72 + (kb ^ (row & 56))];
      }
      #pragma unroll
      for (int qg = 0; qg < 2; ++qg) {
        s4v pf;
        ((unsigned int*)&pf)[0] = pk[qg][k4][0];
        ((unsigned int*)&pf)[1] = pk[qg][k4][1];
        #pragma unroll
        for (int dt = 0; dt < 4; ++dt)
          ot[qg][dt] = mfma16(vf[dt], pf, ot[qg][dt]);
      }
    }

    // off-critical-path: reduce rs/mx across quads, update li, rescale to new ref
    #pragma unroll
    for (int qg = 0; qg < 2; ++qg) {
      float rs = trs[qg];
      rs += __shfl_xor(rs, 16);
      rs += __shfl_xor(rs, 32);
      float mx = tmx[qg];
      mx = fmaxf(mx, __shfl_xor(mx, 16));
      mx = fmaxf(mx, __shfl_xor(mx, 32));
      const float mnew = fmaxf(mi[qg], mx);
      const float c = __builtin_amdgcn_exp2f(mi[qg] - mnew);
      mi[qg] = mnew;
      li[qg] = (li[qg] + rs) * c;
      #pragma unroll
      for (int dt = 0; dt < 4; ++dt) {
        ot[qg][dt][0] *= c; ot[qg][dt][1] *= c;
        ot[qg][dt][2] *= c; ot[qg][dt][3] *= c;
      }
    }
  }

  __syncthreads();   // all waves done reading Ks/Vt
  if (latent) {
    const long pb = (long)(s6 * 256 + qb);
    if (quad == 0) {
      #pragma unroll
      for (int qg = 0; qg < 2; ++qg) {
        mpart[pb * 128 + w * 32 + qg * 16 + l15] = mi[qg];
        lpart[pb * 128 + w * 32 + qg * 16 + l15] = li[qg];
      }
    }
    // O^T straight from regs: Opart_t[(s,qb)][d][q]
    float* obase = Opart + pb * 8192;
    #pragma unroll
    for (int qg = 0; qg < 2; ++qg) {
      const int q = w * 32 + qg * 16 + l15;
      #pragma unroll
      for (int dt = 0; dt < 4; ++dt)
        #pragma unroll
        for (int r = 0; r < 4; ++r)
          obase[(dt * 16 + quad * 4 + r) * 128 + q] = ot[qg][dt][r];
    }
  } else {
    // normalize, transpose via LDS (overlay [128][72] shorts), coalesced store
    #pragma unroll
    for (int qg = 0; qg < 2; ++qg) {
      const float inv = 1.0f / li[qg];
      const int q = w * 32 + qg * 16 + l15;
      #pragma unroll
      for (int dt = 0; dt < 4; ++dt)
        #pragma unroll
        for (int r = 0; r < 4; ++r)
          smem[q * 72 + dt * 16 + quad * 4 + r] = f2bf(ot[qg][dt][r] * inv);
    }
    __syncthreads();
    const int qrow = tid >> 1, half = tid & 1;
    const int b_ = bh >> 4, h_ = bh & 15;
    unsigned short* orow = attn_out + ((long)b_ * NB_N + q0tok + qrow) * NB_DIM + h_ * 64 + half * 32;
    #pragma unroll
    for (int v = 0; v < 4; ++v)
      *(uint4*)(orow + v * 8) = *(const uint4*)&smem[qrow * 72 + half * 32 + v * 8];
  }
}

// ---------------- combine latent split-K partials (transposed Opart layout) ----------------
__global__ __launch_bounds__(256) void k_combine(
    const float* __restrict__ Opart, const float* __restrict__ mpart,
    const float* __restrict__ lpart, unsigned short* __restrict__ attn_out)
{
  __shared__ unsigned short lds[9216];   // [128][72] bf16
  const int qb = blockIdx.x;             // bh*8 + qt
  const int bh = qb >> 3, qt = qb & 7;
  const int b = bh >> 4, h = bh & 15;
  const int t = threadIdx.x;
  const int qq = t & 31;                 // q = qq*4 + qi
  const int dg = t >> 5;                 // d = dg*8 .. +7

  float m[NSPLIT][4], l[NSPLIT][4];
  float mstar[4];
  #pragma unroll
  for (int qi = 0; qi < 4; ++qi) mstar[qi] = NEGF;
  #pragma unroll
  for (int s = 0; s < NSPLIT; ++s) {
    #pragma unroll
    for (int qi = 0; qi < 4; ++qi) {
      m[s][qi] = mpart[(s * 256 + qb) * 128 + qq * 4 + qi];
      l[s][qi] = lpart[(s * 256 + qb) * 128 + qq * 4 + qi];
      mstar[qi] = fmaxf(mstar[qi], m[s][qi]);
    }
  }
  float inv[4];
  #pragma unroll
  for (int qi = 0; qi < 4; ++qi) {
    float lsum = 0.f;
    #pragma unroll
    for (int s = 0; s < NSPLIT; ++s)
      lsum += __builtin_amdgcn_exp2f(m[s][qi] - mstar[qi]) * l[s][qi];
    inv[qi] = 1.0f / lsum;
  }

  float o[8][4];   // [dd][qi]
  #pragma unroll
  for (int dd = 0; dd < 8; ++dd)
    #pragma unroll
    for (int qi = 0; qi < 4; ++qi) o[dd][qi] = 0.f;
  #pragma unroll
  for (int s = 0; s < NSPLIT; ++s) {
    float wgt[4];
    #pragma unroll
    for (int qi = 0; qi < 4; ++qi)
      wgt[qi] = __builtin_amdgcn_exp2f(m[s][qi] - mstar[qi]);
    const float* base = Opart + (long)(s * 256 + qb) * 8192;
    #pragma unroll
    for (int dd = 0; dd < 8; ++dd) {
      float4 v = *(const float4*)(base + (dg * 8 + dd) * 128 + qq * 4);
      o[dd][0] += wgt[0] * v.x; o[dd][1] += wgt[1] * v.y;
      o[dd][2] += wgt[2] * v.z; o[dd][3] += wgt[3] * v.w;
    }
  }
  // transpose through LDS
  #pragma unroll
  for (int qi = 0; qi < 4; ++qi) {
    ushort4 u0, u1;
    u0.x = f2bf(o[0][qi] * inv[qi]); u0.y = f2bf(o[1][qi] * inv[qi]);
    u0.z = f2bf(o[2][qi] * inv[qi]); u0.w = f2bf(o[3][qi] * inv[qi]);
    u1.x = f2bf(o[4][qi] * inv[qi]); u1.y = f2bf(o[5][qi] * inv[qi]);
    u1.z = f2bf(o[6][qi] * inv[qi]); u1.w = f2bf(o[7][qi] * inv[qi]);
    *(ushort4*)&lds[(qq * 4 + qi) * 72 + dg * 8] = u0;
    *(ushort4*)&lds[(qq * 4 + qi) * 72 + dg * 8 + 4] = u1;
  }
  __syncthreads();
  const int qrow = t >> 1, half = t & 1;
  unsigned short* orow = attn_out + ((long)b * NB_N + NB_CTX + qt * 128 + qrow) * NB_DIM + h * 64 + half * 32;
  #pragma unroll
  for (int v = 0; v < 4; ++v)
    *(uint4*)(orow + v * 8) = *(const uint4*)&lds[qrow * 72 + half * 32 + v * 8];
}

extern "C" void kernel_launch(void* const* d_in, const int* in_sizes, int n_in,
                              void* d_out, int out_size, void* d_ws, size_t ws_size,
                              hipStream_t stream)
{
  const float* x    = (const float*)d_in[0];
  const float* Wq   = (const float*)d_in[1];
  const float* Wkv  = (const float*)d_in[2];
  const float* Wo   = (const float*)d_in[3];
  const float* bo   = (const float*)d_in[4];
  const float* ln_g = (const float*)d_in[5];
  const float* ln_b = (const float*)d_in[6];
  float* out = (float*)d_out;

  char* ws = (char*)d_ws;
  unsigned short* xb    = (unsigned short*)(ws);                       // [0,16M)
  unsigned short* WqkvT = (unsigned short*)(ws + (size_t)(16 << 20));  // [16,20M)
  unsigned short* WoT   = (unsigned short*)(ws + (size_t)(20 << 20));  // [20,22M)
  float2*         tab   = (float2*)        (ws + (size_t)(22 << 20));  // [22,23M)
  unsigned short* qfb   = (unsigned short*)(ws + (size_t)(24 << 20));  // [24,40M)
  unsigned short* lkv   = (unsigned short*)(ws + (size_t)(40 << 20));  // [40,56M)
  unsigned short* aout  = (unsigned short*)(ws + (size_t)(56 << 20));  // [56,72M)
  float*          Opart = (float*)         (ws + (size_t)(72 << 20));  // [72,106M)
  float*          mpart = (float*)         (ws + (size_t)(112 << 20)); // [112,113M)
  float*          lpart = (float*)         (ws + (size_t)(113 << 20)); // [113,114M)

  hipLaunchKernelGGL(k_prep, dim3(3328), dim3(256), 0, stream,
                     x, Wq, Wkv, Wo, xb, WqkvT, WoT, tab);
  hipLaunchKernelGGL(k_gemm_qkv, dim3(16, 64), dim3(256), 0, stream,
                     xb, WqkvT, qfb, lkv, tab, ln_g, ln_b);
  hipLaunchKernelGGL(k_attn, dim3(256 * NSPLIT + 768), dim3(256), 0, stream,
                     qfb, lkv, aout, Opart, mpart, lpart);
  hipLaunchKernelGGL(k_combine, dim3(256), dim3(256), 0, stream,
                     Opart, mpart, lpart, aout);
  hipLaunchKernelGGL(k_gemm_bt, dim3(8, 64), dim3(256), 0, stream,
                     aout, WoT, out, bo, 1024, 1024);
}